// Round 4
// baseline (8069.116 us; speedup 1.0000x reference)
//
#include <hip/hip_runtime.h>
#include <math.h>

// ---------------------------------------------------------------------------
// Variance-propagating UNet (density prop), fp32, NHWC.
// Round 3: revert to 1-px/thread mapping (occupancy + L2 reuse), precompute
// w^2 per layer and t[pix]=sum_ci(mu^2+s) per layer; conv inner loop is now
// ~38 VALU per 32 useful FMAs (was ~62).
// ---------------------------------------------------------------------------

__device__ __forceinline__ float softplus_f(float x) { return log1pf(expf(x)); }

__global__ void square_kernel(const float* __restrict__ in,
                              float* __restrict__ out, int n)
{
    int i = blockIdx.x * blockDim.x + threadIdx.x;
    if (i < n) { float v = in[i]; out[i] = v * v; }
}

// t[pix] = sum_ci (mu^2 + s) over source1 (and source2 at crop offset).
// Grid = logical input grid [B,Hin,Win]; source1 layout == logical grid.
__global__ void t_kernel(const float* __restrict__ mu1, const float* __restrict__ s1,
                         const float* __restrict__ mu2, const float* __restrict__ s2,
                         float* __restrict__ t_out,
                         int B, int Hin, int Win, int Cin1, int Cin2,
                         int H2, int W2, int dh, int dw)
{
    int pix = blockIdx.x * blockDim.x + threadIdx.x;
    int total = B * Hin * Win;
    if (pix >= total) return;
    float acc = 0.f;
    {
        const float* mp = mu1 + (size_t)pix * Cin1;
        const float* sp = s1 + (size_t)pix * Cin1;
        for (int ci = 0; ci < Cin1; ci += 4) {
            float4 m = *(const float4*)(mp + ci);
            float4 s = *(const float4*)(sp + ci);
            acc += m.x * m.x + s.x + m.y * m.y + s.y
                 + m.z * m.z + s.z + m.w * m.w + s.w;
        }
    }
    if (Cin2 > 0) {
        int b = pix / (Hin * Win);
        int rem = pix - b * (Hin * Win);
        int h = rem / Win, w = rem - (rem / Win) * Win;
        size_t base = ((size_t)(b * H2 + h + dh) * W2 + (w + dw)) * Cin2;
        const float* mp = mu2 + base;
        const float* sp = s2 + base;
        for (int ci = 0; ci < Cin2; ci += 4) {
            float4 m = *(const float4*)(mp + ci);
            float4 s = *(const float4*)(sp + ci);
            acc += m.x * m.x + s.x + m.y * m.y + s.y
                 + m.z * m.z + s.z + m.w * m.w + s.w;
        }
    }
    t_out[pix] = acc;
}

// First layer: mu = conv3x3(pad(x), w_mu); s = (patch-sum of x^2)*softplus(w_sig); relu.
__global__ void conv_input_relu_kernel(const float* __restrict__ x,
                                       const float* __restrict__ w_mu,
                                       const float* __restrict__ w_sig,
                                       float* __restrict__ mu_out,
                                       float* __restrict__ s_out,
                                       int B, int H, int W, int Cin, int Cout)
{
    int co  = threadIdx.x;
    int pix = blockIdx.x * blockDim.y + threadIdx.y;
    int total = B * H * W;
    if (pix >= total) return;
    int b = pix / (H * W);
    int rem = pix % (H * W);
    int h = rem / W, w = rem % W;

    float mu = 0.f, q = 0.f;
    for (int kh = 0; kh < 3; kh++) {
        int ih = h + kh - 1;
        if (ih < 0 || ih >= H) continue;
        for (int kw = 0; kw < 3; kw++) {
            int iw = w + kw - 1;
            if (iw < 0 || iw >= W) continue;
            const float* xp = x + ((size_t)(b * H + ih) * W + iw) * Cin;
            const float* wp = w_mu + (size_t)((kh * 3 + kw) * Cin) * Cout + co;
            for (int ci = 0; ci < Cin; ci++) {
                float xv = xp[ci];
                mu += xv * wp[(size_t)ci * Cout];
                q  += xv * xv;
            }
        }
    }
    float s = q * softplus_f(w_sig[co]);
    if (!(mu > 0.f)) { mu = 0.f; s = 0.f; }
    size_t oidx = (size_t)pix * Cout + co;
    mu_out[oidx] = mu;
    s_out[oidx]  = s;
}

// Main conv: 1 pixel/thread, 4 co/thread. q from precomputed t; w^2 from w_sq.
// Optional second source (fused skip concat) at crop offset (dh,dw).
__global__ void __launch_bounds__(256)
conv4_kernel(const float* __restrict__ mu1, const float* __restrict__ s1,
             const float* __restrict__ mu2, const float* __restrict__ s2,
             const float* __restrict__ tq,
             const float* __restrict__ w_mu, const float* __restrict__ w_sq,
             const float* __restrict__ w_sig,
             float* __restrict__ mu_out, float* __restrict__ s_out,
             int B, int Hin, int Win, int Cin1, int Cin2,
             int H2, int W2, int dh, int dw,
             int Hout, int Wout, int Cout, int pad, int do_relu)
{
    const int cog = threadIdx.x * 4;
    int pix = blockIdx.x * blockDim.y + threadIdx.y;
    int total = B * Hout * Wout;
    if (pix >= total) return;
    int b = pix / (Hout * Wout);
    int rem = pix - b * (Hout * Wout);
    int h = rem / Wout;
    int w = rem - h * Wout;
    const int Cin = Cin1 + Cin2;

    float4 amu = make_float4(0.f, 0.f, 0.f, 0.f);
    float4 asa = make_float4(0.f, 0.f, 0.f, 0.f);
    float q = 0.f;

    for (int kh = 0; kh < 3; kh++) {
        int ih = h + kh - pad;
        if ((unsigned)ih >= (unsigned)Hin) continue;
        for (int kw = 0; kw < 3; kw++) {
            int iw = w + kw - pad;
            if ((unsigned)iw >= (unsigned)Win) continue;
            q += tq[(size_t)(b * Hin + ih) * Win + iw];
            const size_t wtap = (size_t)((kh * 3 + kw) * Cin) * Cout + cog;
            const float* __restrict__ wp  = w_mu + wtap;
            const float* __restrict__ wwp = w_sq + wtap;
            {
                size_t base = ((size_t)(b * Hin + ih) * Win + iw) * Cin1;
                const float* mp = mu1 + base;
                const float* sp = s1 + base;
                for (int ci = 0; ci < Cin1; ci += 4) {
                    float4 m4 = *(const float4*)(mp + ci);
                    float4 s4 = *(const float4*)(sp + ci);
                    const float* wb  = wp  + (size_t)ci * Cout;
                    const float* wwb = wwp + (size_t)ci * Cout;
                    float4 w0 = *(const float4*)(wb);
                    float4 w1 = *(const float4*)(wb + Cout);
                    float4 w2 = *(const float4*)(wb + 2 * Cout);
                    float4 w3 = *(const float4*)(wb + 3 * Cout);
                    float4 u0 = *(const float4*)(wwb);
                    float4 u1 = *(const float4*)(wwb + Cout);
                    float4 u2 = *(const float4*)(wwb + 2 * Cout);
                    float4 u3 = *(const float4*)(wwb + 3 * Cout);
                    amu.x += m4.x*w0.x + m4.y*w1.x + m4.z*w2.x + m4.w*w3.x;
                    amu.y += m4.x*w0.y + m4.y*w1.y + m4.z*w2.y + m4.w*w3.y;
                    amu.z += m4.x*w0.z + m4.y*w1.z + m4.z*w2.z + m4.w*w3.z;
                    amu.w += m4.x*w0.w + m4.y*w1.w + m4.z*w2.w + m4.w*w3.w;
                    asa.x += s4.x*u0.x + s4.y*u1.x + s4.z*u2.x + s4.w*u3.x;
                    asa.y += s4.x*u0.y + s4.y*u1.y + s4.z*u2.y + s4.w*u3.y;
                    asa.z += s4.x*u0.z + s4.y*u1.z + s4.z*u2.z + s4.w*u3.z;
                    asa.w += s4.x*u0.w + s4.y*u1.w + s4.z*u2.w + s4.w*u3.w;
                }
            }
            if (Cin2 > 0) {
                size_t base = ((size_t)(b * H2 + ih + dh) * W2 + (iw + dw)) * Cin2;
                const float* mp = mu2 + base;
                const float* sp = s2 + base;
                const float* wp2  = wp  + (size_t)Cin1 * Cout;
                const float* wwp2 = wwp + (size_t)Cin1 * Cout;
                for (int ci = 0; ci < Cin2; ci += 4) {
                    float4 m4 = *(const float4*)(mp + ci);
                    float4 s4 = *(const float4*)(sp + ci);
                    const float* wb  = wp2  + (size_t)ci * Cout;
                    const float* wwb = wwp2 + (size_t)ci * Cout;
                    float4 w0 = *(const float4*)(wb);
                    float4 w1 = *(const float4*)(wb + Cout);
                    float4 w2 = *(const float4*)(wb + 2 * Cout);
                    float4 w3 = *(const float4*)(wb + 3 * Cout);
                    float4 u0 = *(const float4*)(wwb);
                    float4 u1 = *(const float4*)(wwb + Cout);
                    float4 u2 = *(const float4*)(wwb + 2 * Cout);
                    float4 u3 = *(const float4*)(wwb + 3 * Cout);
                    amu.x += m4.x*w0.x + m4.y*w1.x + m4.z*w2.x + m4.w*w3.x;
                    amu.y += m4.x*w0.y + m4.y*w1.y + m4.z*w2.y + m4.w*w3.y;
                    amu.z += m4.x*w0.z + m4.y*w1.z + m4.z*w2.z + m4.w*w3.z;
                    amu.w += m4.x*w0.w + m4.y*w1.w + m4.z*w2.w + m4.w*w3.w;
                    asa.x += s4.x*u0.x + s4.y*u1.x + s4.z*u2.x + s4.w*u3.x;
                    asa.y += s4.x*u0.y + s4.y*u1.y + s4.z*u2.y + s4.w*u3.y;
                    asa.z += s4.x*u0.z + s4.y*u1.z + s4.z*u2.z + s4.w*u3.z;
                    asa.w += s4.x*u0.w + s4.y*u1.w + s4.z*u2.w + s4.w*u3.w;
                }
            }
        }
    }

    float4 sg = *(const float4*)(w_sig + cog);
    float4 so;
    so.x = q * softplus_f(sg.x) + asa.x;
    so.y = q * softplus_f(sg.y) + asa.y;
    so.z = q * softplus_f(sg.z) + asa.z;
    so.w = q * softplus_f(sg.w) + asa.w;
    if (do_relu) {
        if (!(amu.x > 0.f)) { amu.x = 0.f; so.x = 0.f; }
        if (!(amu.y > 0.f)) { amu.y = 0.f; so.y = 0.f; }
        if (!(amu.z > 0.f)) { amu.z = 0.f; so.z = 0.f; }
        if (!(amu.w > 0.f)) { amu.w = 0.f; so.w = 0.f; }
    }
    size_t oidx = (size_t)pix * Cout + cog;
    *(float4*)(mu_out + oidx) = amu;
    *(float4*)(s_out  + oidx) = so;
}

// conv_inter fused with zero-insertion unpool (1/2/4 live taps), t-based q,
// precomputed w^2.
__global__ void __launch_bounds__(256)
conv_unpool_fused(const float* __restrict__ mu_in,
                  const float* __restrict__ s_in,
                  const float* __restrict__ tq,
                  const float* __restrict__ w_mu,
                  const float* __restrict__ w_sq,
                  const float* __restrict__ w_sig,
                  float* __restrict__ mu_out,
                  float* __restrict__ s_out,
                  int B, int Hin, int Win, int Cin,
                  int Hout, int Wout, int Cout,
                  int do_relu)
{
    int cog = threadIdx.x * 4;
    int pix = blockIdx.x * blockDim.y + threadIdx.y;
    int total = B * Hout * Wout;
    if (pix >= total) return;
    int b = pix / (Hout * Wout);
    int rem = pix - b * (Hout * Wout);
    int ho = rem / Wout, wo = rem - (rem / Wout) * Wout;

    int khs[2], ihs[2], nkh;
    if (ho & 1) { nkh = 2; khs[0] = 0; ihs[0] = (ho - 1) >> 1; khs[1] = 2; ihs[1] = (ho + 1) >> 1; }
    else        { nkh = 1; khs[0] = 1; ihs[0] = ho >> 1; }
    int kws[2], iws[2], nkw;
    if (wo & 1) { nkw = 2; kws[0] = 0; iws[0] = (wo - 1) >> 1; kws[1] = 2; iws[1] = (wo + 1) >> 1; }
    else        { nkw = 1; kws[0] = 1; iws[0] = wo >> 1; }

    float4 amu = make_float4(0.f, 0.f, 0.f, 0.f);
    float4 asa = make_float4(0.f, 0.f, 0.f, 0.f);
    float q = 0.f;

    for (int a = 0; a < nkh; a++) {
        for (int c = 0; c < nkw; c++) {
            q += tq[(size_t)(b * Hin + ihs[a]) * Win + iws[c]];
            size_t base = ((size_t)(b * Hin + ihs[a]) * Win + iws[c]) * Cin;
            const float* mp = mu_in + base;
            const float* sp = s_in + base;
            const size_t wtap = (size_t)((khs[a] * 3 + kws[c]) * Cin) * Cout + cog;
            const float* wp  = w_mu + wtap;
            const float* wwp = w_sq + wtap;
            for (int ci = 0; ci < Cin; ci += 4) {
                float4 m4 = *(const float4*)(mp + ci);
                float4 s4 = *(const float4*)(sp + ci);
                const float* wb  = wp  + (size_t)ci * Cout;
                const float* wwb = wwp + (size_t)ci * Cout;
                float4 w0 = *(const float4*)(wb);
                float4 w1 = *(const float4*)(wb + Cout);
                float4 w2 = *(const float4*)(wb + 2 * Cout);
                float4 w3 = *(const float4*)(wb + 3 * Cout);
                float4 u0 = *(const float4*)(wwb);
                float4 u1 = *(const float4*)(wwb + Cout);
                float4 u2 = *(const float4*)(wwb + 2 * Cout);
                float4 u3 = *(const float4*)(wwb + 3 * Cout);
                amu.x += m4.x*w0.x + m4.y*w1.x + m4.z*w2.x + m4.w*w3.x;
                amu.y += m4.x*w0.y + m4.y*w1.y + m4.z*w2.y + m4.w*w3.y;
                amu.z += m4.x*w0.z + m4.y*w1.z + m4.z*w2.z + m4.w*w3.z;
                amu.w += m4.x*w0.w + m4.y*w1.w + m4.z*w2.w + m4.w*w3.w;
                asa.x += s4.x*u0.x + s4.y*u1.x + s4.z*u2.x + s4.w*u3.x;
                asa.y += s4.x*u0.y + s4.y*u1.y + s4.z*u2.y + s4.w*u3.y;
                asa.z += s4.x*u0.z + s4.y*u1.z + s4.z*u2.z + s4.w*u3.z;
                asa.w += s4.x*u0.w + s4.y*u1.w + s4.z*u2.w + s4.w*u3.w;
            }
        }
    }
    float4 sg = *(const float4*)(w_sig + cog);
    float4 so;
    so.x = q * softplus_f(sg.x) + asa.x;
    so.y = q * softplus_f(sg.y) + asa.y;
    so.z = q * softplus_f(sg.z) + asa.z;
    so.w = q * softplus_f(sg.w) + asa.w;
    if (do_relu) {
        if (!(amu.x > 0.f)) { amu.x = 0.f; so.x = 0.f; }
        if (!(amu.y > 0.f)) { amu.y = 0.f; so.y = 0.f; }
        if (!(amu.z > 0.f)) { amu.z = 0.f; so.z = 0.f; }
        if (!(amu.w > 0.f)) { amu.w = 0.f; so.w = 0.f; }
    }
    size_t oidx = (size_t)pix * Cout + cog;
    *(float4*)(mu_out + oidx) = amu;
    *(float4*)(s_out + oidx)  = so;
}

// 2x2/stride-2 argmax pool; gather s at argmax.
__global__ void pool_kernel(const float* __restrict__ mu_in,
                            const float* __restrict__ s_in,
                            float* __restrict__ mu_out,
                            float* __restrict__ s_out,
                            int B, int H, int W, int C)
{
    int Ho = H / 2, Wo = W / 2;
    size_t total = (size_t)B * Ho * Wo * C;
    size_t idx = (size_t)blockIdx.x * blockDim.x + threadIdx.x;
    if (idx >= total) return;
    int c = idx % C;
    size_t t = idx / C;
    int w = t % Wo; t /= Wo;
    int h = t % Ho;
    int b = t / Ho;
    size_t i0 = ((size_t)(b * H + 2 * h) * W + 2 * w) * C + c;
    size_t rowStride = (size_t)W * C;
    float m00 = mu_in[i0], m01 = mu_in[i0 + C];
    float m10 = mu_in[i0 + rowStride], m11 = mu_in[i0 + rowStride + C];
    int best = 0; float bm = m00;
    if (m01 > bm) { bm = m01; best = 1; }
    if (m10 > bm) { bm = m10; best = 2; }
    if (m11 > bm) { bm = m11; best = 3; }
    size_t off = (size_t)(best >> 1) * rowStride + (size_t)(best & 1) * C;
    mu_out[idx] = bm;
    s_out[idx]  = s_in[i0 + off];
}

// 1x1 conv_inter (Cin -> 2, no relu) fused with C=2 softmax density propagation.
__global__ void final_kernel(const float* __restrict__ mu_in,
                             const float* __restrict__ s_in,
                             const float* __restrict__ w_mu,
                             const float* __restrict__ w_sig,
                             float* __restrict__ out,
                             int B, int H, int W, int Cin)
{
    int pix = blockIdx.x * blockDim.x + threadIdx.x;
    int total = B * H * W;
    if (pix >= total) return;
    const float* mp = mu_in + (size_t)pix * Cin;
    const float* sp = s_in + (size_t)pix * Cin;
    float mu0 = 0.f, mu1 = 0.f, s0a = 0.f, s1a = 0.f, q = 0.f;
    for (int ci = 0; ci < Cin; ci += 4) {
        float4 m = *(const float4*)(mp + ci);
        float4 s = *(const float4*)(sp + ci);
        float4 wa = *(const float4*)(w_mu + ci * 2);
        float4 wb = *(const float4*)(w_mu + ci * 2 + 4);
        mu0 += m.x * wa.x + m.y * wa.z + m.z * wb.x + m.w * wb.z;
        mu1 += m.x * wa.y + m.y * wa.w + m.z * wb.y + m.w * wb.w;
        s0a += s.x * (wa.x * wa.x) + s.y * (wa.z * wa.z) + s.z * (wb.x * wb.x) + s.w * (wb.z * wb.z);
        s1a += s.x * (wa.y * wa.y) + s.y * (wa.w * wa.w) + s.z * (wb.y * wb.y) + s.w * (wb.w * wb.w);
        q += m.x * m.x + s.x + m.y * m.y + s.y + m.z * m.z + s.z + m.w * m.w + s.w;
    }
    float s0 = q * softplus_f(w_sig[0]) + s0a;
    float s1 = q * softplus_f(w_sig[1]) + s1a;
    float mx = fmaxf(mu0, mu1);
    float e0 = expf(mu0 - mx), e1 = expf(mu1 - mx);
    float inv = 1.f / (e0 + e1);
    float p0 = e0 * inv, p1 = e1 * inv;
    float g00 = p0 - p0 * p0, g01 = -p0 * p1;
    float g10 = -p1 * p0,     g11 = p1 - p1 * p1;
    float so0 = g00 * g00 * s0 + g01 * g01 * s1;
    float so1 = g10 * g10 * s0 + g11 * g11 * s1;
    out[(size_t)pix * 2]     = p0;
    out[(size_t)pix * 2 + 1] = p1;
    size_t off = (size_t)total * 2;
    out[off + (size_t)pix * 2]     = so0;
    out[off + (size_t)pix * 2 + 1] = so1;
}

// ---------------------------------------------------------------------------

extern "C" void kernel_launch(void* const* d_in, const int* in_sizes, int n_in,
                              void* d_out, int out_size, void* d_ws, size_t ws_size,
                              hipStream_t stream)
{
    const float* x = (const float*)d_in[0];
    enum { E1A, E1B, E2A, E2B, BA, BB, D2U, D2A, D2B, D1U, D1A, D1B, FIN, NW };
    const float* wmu[NW];
    const float* wsig[NW];
    for (int i = 0; i < NW; i++) {
        wmu[i]  = (const float*)d_in[1 + 2 * i];
        wsig[i] = (const float*)d_in[2 + 2 * i];
    }

    const int B = 4;
    const size_t BUFSZ = 4194304;             // max live tensor: 4*128*128*64
    float* ws = (float*)d_ws;
    float* Amu = ws;
    float* As  = ws + BUFSZ;
    float* Bmu = ws + 2 * BUFSZ;
    float* Bs  = ws + 3 * BUFSZ;
    float* E1mu = ws + 4 * BUFSZ;             // 4*128*128*64 = 4194304
    float* E1s  = E1mu + 4194304;
    float* E2mu = E1s + 4194304;              // 4*64*64*128 = 2097152
    float* E2s  = E2mu + 2097152;
    float* wwb  = E2s + 2097152;              // squared weights, 2064384 floats
    float* tbuf = wwb + 2064384;              // up to 65536 floats

    // squared-weight sub-buffers (11 conv_inter layers)
    const int wwn[11] = {36864, 73728, 147456, 294912, 589824,
                         294912, 294912, 147456, 73728, 73728, 36864};
    const int wwl[11] = {E1B, E2A, E2B, BA, BB, D2U, D2A, D2B, D1U, D1A, D1B};
    float* wwp[NW];
    {
        size_t off = 0;
        for (int i = 0; i < 11; i++) {
            wwp[wwl[i]] = wwb + off;
            square_kernel<<<dim3((wwn[i] + 255) / 256), dim3(256), 0, stream>>>(
                wmu[wwl[i]], wwb + off, wwn[i]);
            off += wwn[i];
        }
    }

    auto launch_t = [&](const float* mi, const float* si, int ci1,
                        const float* me, const float* se, int ci2,
                        int h2, int w2, int dh, int dw,
                        int hi, int wi) {
        int npix = B * hi * wi;
        t_kernel<<<dim3((npix + 255) / 256), dim3(256), 0, stream>>>(
            mi, si, me, se, tbuf, B, hi, wi, ci1, ci2, h2, w2, dh, dw);
    };

    auto launch_conv = [&](const float* mi, const float* si,
                           int hi, int wi, int ci,
                           int ho, int wo, int co,
                           int pad, int relu, int widx,
                           float* mo, float* so) {
        launch_t(mi, si, ci, nullptr, nullptr, 0, 0, 0, 0, 0, hi, wi);
        int totalPix = B * ho * wo;
        int tx = co / 4;
        int ty = 256 / tx;
        dim3 blk(tx, ty);
        dim3 grd((totalPix + ty - 1) / ty);
        conv4_kernel<<<grd, blk, 0, stream>>>(
            mi, si, nullptr, nullptr, tbuf, wmu[widx], wwp[widx], wsig[widx], mo, so,
            B, hi, wi, ci, 0, 0, 0, 0, 0, ho, wo, co, pad, relu);
    };

    auto launch_conv2 = [&](const float* mi, const float* si, int ci1,
                            const float* me, const float* se, int ci2,
                            int h2, int w2, int dh, int dw,
                            int hi, int wi, int ho, int wo, int co,
                            int pad, int relu, int widx,
                            float* mo, float* so) {
        launch_t(mi, si, ci1, me, se, ci2, h2, w2, dh, dw, hi, wi);
        int totalPix = B * ho * wo;
        int tx = co / 4;
        int ty = 256 / tx;
        dim3 blk(tx, ty);
        dim3 grd((totalPix + ty - 1) / ty);
        conv4_kernel<<<grd, blk, 0, stream>>>(
            mi, si, me, se, tbuf, wmu[widx], wwp[widx], wsig[widx], mo, so,
            B, hi, wi, ci1, ci2, h2, w2, dh, dw, ho, wo, co, pad, relu);
    };

    auto launch_conv_unpool = [&](const float* mi, const float* si,
                                  int hi, int wi, int ci,
                                  int ho, int wo, int co,
                                  int relu, int widx,
                                  float* mo, float* so) {
        launch_t(mi, si, ci, nullptr, nullptr, 0, 0, 0, 0, 0, hi, wi);
        int totalPix = B * ho * wo;
        int tx = co / 4;
        int ty = 256 / tx;
        dim3 blk(tx, ty);
        dim3 grd((totalPix + ty - 1) / ty);
        conv_unpool_fused<<<grd, blk, 0, stream>>>(
            mi, si, tbuf, wmu[widx], wwp[widx], wsig[widx], mo, so,
            B, hi, wi, ci, ho, wo, co, relu);
    };

    // ---- encoder level 1 ----
    {
        int totalPix = B * 128 * 128;
        conv_input_relu_kernel<<<dim3((totalPix + 3) / 4), dim3(64, 4), 0, stream>>>(
            x, wmu[E1A], wsig[E1A], Amu, As, B, 128, 128, 3, 64);
    }
    launch_conv(Amu, As, 128, 128, 64, 128, 128, 64, 1, 1, E1B, E1mu, E1s);
    {
        size_t total = (size_t)B * 64 * 64 * 64;
        pool_kernel<<<dim3((total + 255) / 256), dim3(256), 0, stream>>>(
            E1mu, E1s, Bmu, Bs, B, 128, 128, 64);
    }
    // ---- encoder level 2 ----
    launch_conv(Bmu, Bs, 64, 64, 64, 64, 64, 128, 1, 1, E2A, Amu, As);
    launch_conv(Amu, As, 64, 64, 128, 64, 64, 128, 1, 1, E2B, E2mu, E2s);
    {
        size_t total = (size_t)B * 32 * 32 * 128;
        pool_kernel<<<dim3((total + 255) / 256), dim3(256), 0, stream>>>(
            E2mu, E2s, Amu, As, B, 64, 64, 128);
    }
    // ---- bottleneck ----
    launch_conv(Amu, As, 32, 32, 128, 32, 32, 256, 1, 1, BA, Bmu, Bs);
    launch_conv(Bmu, Bs, 32, 32, 256, 32, 32, 256, 1, 1, BB, Amu, As);
    // ---- decoder level 2 ----
    launch_conv_unpool(Amu, As, 32, 32, 256, 63, 63, 128, 1, D2U, Bmu, Bs);
    launch_conv2(Bmu, Bs, 128, E2mu, E2s, 128, 64, 64, 0, 0,
                 63, 63, 63, 63, 128, 1, 1, D2A, Amu, As);
    launch_conv(Amu, As, 63, 63, 128, 63, 63, 128, 1, 1, D2B, Bmu, Bs);
    // ---- decoder level 1 ----
    launch_conv_unpool(Bmu, Bs, 63, 63, 128, 125, 125, 64, 1, D1U, Amu, As);
    launch_conv2(Amu, As, 64, E1mu, E1s, 64, 128, 128, 1, 1,
                 125, 125, 125, 125, 64, 1, 1, D1A, Bmu, Bs);
    launch_conv(Bmu, Bs, 125, 125, 64, 125, 125, 64, 1, 1, D1B, Amu, As);
    // ---- final 1x1 + softmax prop ----
    {
        int totalPix = B * 125 * 125;
        final_kernel<<<dim3((totalPix + 63) / 64), dim3(64), 0, stream>>>(
            Amu, As, wmu[FIN], wsig[FIN], (float*)d_out, B, 125, 125, 64);
    }
}

// Round 6
// 4663.960 us; speedup vs baseline: 1.7301x; 1.7301x over previous
//
#include <hip/hip_runtime.h>
#include <math.h>

// ---------------------------------------------------------------------------
// Variance-propagating UNet (density prop), NHWC.
// Round 5: HYBRID. mu-chain stays fp32 vector (exact relu gates — bf16 mu
// caused gate flips -> 4e5 s-error last round). s-conv = bf16 MFMA with s
// stored as hi+lo bf16 pair (2 MFMAs -> ~fp32 s precision), LDS-free
// per-lane fragment loads. q via fp32 t/q9 precompute.
// ---------------------------------------------------------------------------

typedef __attribute__((ext_vector_type(8))) short short8;
typedef __attribute__((ext_vector_type(4))) float floatx4;

__device__ __forceinline__ float softplus_f(float x) { return log1pf(expf(x)); }

__device__ __forceinline__ unsigned short f2bf(float x) {
    unsigned int u = __float_as_uint(x);
    u = (u + 0x7FFF + ((u >> 16) & 1)) >> 16;
    return (unsigned short)u;
}
__device__ __forceinline__ float bfval(unsigned short h) {
    return __uint_as_float((unsigned int)h << 16);
}
__device__ __forceinline__ float bf2f_lo(unsigned int u) {
    return __uint_as_float(u << 16);
}
__device__ __forceinline__ float bf2f_hi(unsigned int u) {
    return __uint_as_float(u & 0xFFFF0000u);
}

// ---- weight prep: wTsq[tap][co][ci] = bf16(w[tap][ci][co]^2)
__global__ void wprep_kernel(const float* __restrict__ w,
                             unsigned short* __restrict__ wTsq,
                             int Cin, int Cout, int n)
{
    int idx = blockIdx.x * blockDim.x + threadIdx.x;
    if (idx >= n) return;
    int per = Cin * Cout;
    int tap = idx / per;
    int rem = idx - tap * per;
    int co = rem / Cin;
    int ci = rem - co * Cin;
    float v = w[(size_t)(tap * Cin + ci) * Cout + co];
    wTsq[idx] = f2bf(v * v);
}

__global__ void sp_kernel(const float* __restrict__ wsig,
                          float* __restrict__ sp, int n)
{
    int i = blockIdx.x * blockDim.x + threadIdx.x;
    if (i < n) sp[i] = softplus_f(wsig[i]);
}

// ---- t from fp32 mu + hi/lo bf16 s (optional 2nd source at crop offset)
__global__ void t_mixed_kernel(const float* __restrict__ mu1,
                               const unsigned short* __restrict__ s1h,
                               const unsigned short* __restrict__ s1l,
                               const float* __restrict__ mu2,
                               const unsigned short* __restrict__ s2h,
                               const unsigned short* __restrict__ s2l,
                               float* __restrict__ t_out,
                               int B_, int Hin, int Win, int Cin1, int Cin2,
                               int H2, int W2, int dh, int dw)
{
    int pix = blockIdx.x * blockDim.x + threadIdx.x;
    int total = B_ * Hin * Win;
    if (pix >= total) return;
    float acc = 0.f;
    {
        const float* mp = mu1 + (size_t)pix * Cin1;
        const unsigned short* sh = s1h + (size_t)pix * Cin1;
        const unsigned short* sl = s1l + (size_t)pix * Cin1;
        for (int ci = 0; ci < Cin1; ci += 8) {
            float4 m0 = *(const float4*)(mp + ci);
            float4 m1 = *(const float4*)(mp + ci + 4);
            uint4 vh = *(const uint4*)(sh + ci);
            uint4 vl = *(const uint4*)(sl + ci);
            acc += m0.x*m0.x + m0.y*m0.y + m0.z*m0.z + m0.w*m0.w
                 + m1.x*m1.x + m1.y*m1.y + m1.z*m1.z + m1.w*m1.w;
            acc += bf2f_lo(vh.x) + bf2f_hi(vh.x) + bf2f_lo(vh.y) + bf2f_hi(vh.y)
                 + bf2f_lo(vh.z) + bf2f_hi(vh.z) + bf2f_lo(vh.w) + bf2f_hi(vh.w);
            acc += bf2f_lo(vl.x) + bf2f_hi(vl.x) + bf2f_lo(vl.y) + bf2f_hi(vl.y)
                 + bf2f_lo(vl.z) + bf2f_hi(vl.z) + bf2f_lo(vl.w) + bf2f_hi(vl.w);
        }
    }
    if (Cin2 > 0) {
        int b = pix / (Hin * Win);
        int rem = pix - b * (Hin * Win);
        int h = rem / Win, w = rem - (rem / Win) * Win;
        size_t base = ((size_t)(b * H2 + h + dh) * W2 + (w + dw)) * Cin2;
        const float* mp = mu2 + base;
        const unsigned short* sh = s2h + base;
        const unsigned short* sl = s2l + base;
        for (int ci = 0; ci < Cin2; ci += 8) {
            float4 m0 = *(const float4*)(mp + ci);
            float4 m1 = *(const float4*)(mp + ci + 4);
            uint4 vh = *(const uint4*)(sh + ci);
            uint4 vl = *(const uint4*)(sl + ci);
            acc += m0.x*m0.x + m0.y*m0.y + m0.z*m0.z + m0.w*m0.w
                 + m1.x*m1.x + m1.y*m1.y + m1.z*m1.z + m1.w*m1.w;
            acc += bf2f_lo(vh.x) + bf2f_hi(vh.x) + bf2f_lo(vh.y) + bf2f_hi(vh.y)
                 + bf2f_lo(vh.z) + bf2f_hi(vh.z) + bf2f_lo(vh.w) + bf2f_hi(vh.w);
            acc += bf2f_lo(vl.x) + bf2f_hi(vl.x) + bf2f_lo(vl.y) + bf2f_hi(vl.y)
                 + bf2f_lo(vl.z) + bf2f_hi(vl.z) + bf2f_lo(vl.w) + bf2f_hi(vl.w);
        }
    }
    t_out[pix] = acc;
}

// ---- t from fp32 mu + fp32 s (for unpool-conv inputs)
__global__ void t_f32_kernel(const float* __restrict__ mu1, const float* __restrict__ s1,
                             float* __restrict__ t_out, int total, int Cin)
{
    int pix = blockIdx.x * blockDim.x + threadIdx.x;
    if (pix >= total) return;
    const float* mp = mu1 + (size_t)pix * Cin;
    const float* sp = s1 + (size_t)pix * Cin;
    float acc = 0.f;
    for (int ci = 0; ci < Cin; ci += 4) {
        float4 m = *(const float4*)(mp + ci);
        float4 s = *(const float4*)(sp + ci);
        acc += m.x * m.x + s.x + m.y * m.y + s.y
             + m.z * m.z + s.z + m.w * m.w + s.w;
    }
    t_out[pix] = acc;
}

// ---- q9: sum t over valid 3x3 taps (pad=1)
__global__ void q9_kernel(const float* __restrict__ t_in,
                          float* __restrict__ q9, int B_, int H, int W)
{
    int pix = blockIdx.x * blockDim.x + threadIdx.x;
    int total = B_ * H * W;
    if (pix >= total) return;
    int b = pix / (H * W);
    int rem = pix - b * (H * W);
    int h = rem / W, w = rem - (rem / W) * W;
    float acc = 0.f;
    for (int kh = 0; kh < 3; kh++) {
        int ih = h + kh - 1;
        if ((unsigned)ih >= (unsigned)H) continue;
        for (int kw = 0; kw < 3; kw++) {
            int iw = w + kw - 1;
            if ((unsigned)iw >= (unsigned)W) continue;
            acc += t_in[(size_t)(b * H + ih) * W + iw];
        }
    }
    q9[pix] = acc;
}

// ---- mu conv: fp32 vector, 8 cout/thread, 1 px/thread, optional 2nd source,
// relu'd fp32 output (this IS the gate for the s kernel).
__global__ void __launch_bounds__(256)
muconv_kernel(const float* __restrict__ mu1, const float* __restrict__ mu2,
              const float* __restrict__ w_mu,
              float* __restrict__ mu_out,
              int B_, int H, int W, int Cin1, int Cin2,
              int H2, int W2, int dh, int dw, int Cout)
{
    const int cog = threadIdx.x * 8;
    int pix = blockIdx.x * blockDim.y + threadIdx.y;
    int total = B_ * H * W;
    if (pix >= total) return;
    int b = pix / (H * W);
    int rem = pix - b * (H * W);
    int h = rem / W;
    int w = rem - h * W;
    const int Cin = Cin1 + Cin2;

    float acc[8];
#pragma unroll
    for (int i = 0; i < 8; i++) acc[i] = 0.f;

    for (int kh = 0; kh < 3; kh++) {
        int ih = h + kh - 1;
        if ((unsigned)ih >= (unsigned)H) continue;
        for (int kw = 0; kw < 3; kw++) {
            int iw = w + kw - 1;
            if ((unsigned)iw >= (unsigned)W) continue;
            const float* __restrict__ wp = w_mu + (size_t)((kh * 3 + kw) * Cin) * Cout + cog;
            {
                const float* mp = mu1 + ((size_t)(b * H + ih) * W + iw) * Cin1;
                for (int ci = 0; ci < Cin1; ci += 4) {
                    float4 m4 = *(const float4*)(mp + ci);
                    const float* wb = wp + (size_t)ci * Cout;
                    float4 a0 = *(const float4*)(wb);
                    float4 a1 = *(const float4*)(wb + 4);
                    float4 b0 = *(const float4*)(wb + Cout);
                    float4 b1 = *(const float4*)(wb + Cout + 4);
                    float4 c0 = *(const float4*)(wb + 2 * Cout);
                    float4 c1 = *(const float4*)(wb + 2 * Cout + 4);
                    float4 d0 = *(const float4*)(wb + 3 * Cout);
                    float4 d1 = *(const float4*)(wb + 3 * Cout + 4);
                    acc[0] += m4.x*a0.x + m4.y*b0.x + m4.z*c0.x + m4.w*d0.x;
                    acc[1] += m4.x*a0.y + m4.y*b0.y + m4.z*c0.y + m4.w*d0.y;
                    acc[2] += m4.x*a0.z + m4.y*b0.z + m4.z*c0.z + m4.w*d0.z;
                    acc[3] += m4.x*a0.w + m4.y*b0.w + m4.z*c0.w + m4.w*d0.w;
                    acc[4] += m4.x*a1.x + m4.y*b1.x + m4.z*c1.x + m4.w*d1.x;
                    acc[5] += m4.x*a1.y + m4.y*b1.y + m4.z*c1.y + m4.w*d1.y;
                    acc[6] += m4.x*a1.z + m4.y*b1.z + m4.z*c1.z + m4.w*d1.z;
                    acc[7] += m4.x*a1.w + m4.y*b1.w + m4.z*c1.w + m4.w*d1.w;
                }
            }
            if (Cin2 > 0) {
                const float* mp = mu2 + ((size_t)(b * H2 + ih + dh) * W2 + (iw + dw)) * Cin2;
                const float* __restrict__ wp2 = wp + (size_t)Cin1 * Cout;
                for (int ci = 0; ci < Cin2; ci += 4) {
                    float4 m4 = *(const float4*)(mp + ci);
                    const float* wb = wp2 + (size_t)ci * Cout;
                    float4 a0 = *(const float4*)(wb);
                    float4 a1 = *(const float4*)(wb + 4);
                    float4 b0 = *(const float4*)(wb + Cout);
                    float4 b1 = *(const float4*)(wb + Cout + 4);
                    float4 c0 = *(const float4*)(wb + 2 * Cout);
                    float4 c1 = *(const float4*)(wb + 2 * Cout + 4);
                    float4 d0 = *(const float4*)(wb + 3 * Cout);
                    float4 d1 = *(const float4*)(wb + 3 * Cout + 4);
                    acc[0] += m4.x*a0.x + m4.y*b0.x + m4.z*c0.x + m4.w*d0.x;
                    acc[1] += m4.x*a0.y + m4.y*b0.y + m4.z*c0.y + m4.w*d0.y;
                    acc[2] += m4.x*a0.z + m4.y*b0.z + m4.z*c0.z + m4.w*d0.z;
                    acc[3] += m4.x*a0.w + m4.y*b0.w + m4.z*c0.w + m4.w*d0.w;
                    acc[4] += m4.x*a1.x + m4.y*b1.x + m4.z*c1.x + m4.w*d1.x;
                    acc[5] += m4.x*a1.y + m4.y*b1.y + m4.z*c1.y + m4.w*d1.y;
                    acc[6] += m4.x*a1.z + m4.y*b1.z + m4.z*c1.z + m4.w*d1.z;
                    acc[7] += m4.x*a1.w + m4.y*b1.w + m4.z*c1.w + m4.w*d1.w;
                }
            }
        }
    }
    size_t o = (size_t)pix * Cout + cog;
    float4 r0, r1;
    r0.x = fmaxf(acc[0], 0.f); r0.y = fmaxf(acc[1], 0.f);
    r0.z = fmaxf(acc[2], 0.f); r0.w = fmaxf(acc[3], 0.f);
    r1.x = fmaxf(acc[4], 0.f); r1.y = fmaxf(acc[5], 0.f);
    r1.z = fmaxf(acc[6], 0.f); r1.w = fmaxf(acc[7], 0.f);
    *(float4*)(mu_out + o) = r0;
    *(float4*)(mu_out + o + 4) = r1;
}

// ---- s conv via bf16 MFMA, LDS-free. Each wave: 16 pixels x 64 cout.
// s stored as hi+lo bf16 pair -> 2 MFMAs per (chunk, n-tile).
// s_out = (mu_out>0) ? q9*softplus + sum s*w^2 : 0.
__global__ void __launch_bounds__(256)
smfma_kernel(const unsigned short* __restrict__ s1h, const unsigned short* __restrict__ s1l,
             const unsigned short* __restrict__ s2h, const unsigned short* __restrict__ s2l,
             const float* __restrict__ q9v,
             const unsigned short* __restrict__ wTsq,
             const float* __restrict__ spv_,
             const float* __restrict__ muG,
             unsigned short* __restrict__ outH, unsigned short* __restrict__ outL,
             float* __restrict__ outF,
             int B_, int H, int W, int Cin1, int Cin2,
             int H2, int W2, int dh, int dw, int Cout)
{
    const int lane = threadIdx.x & 63;
    const int wave = threadIdx.x >> 6;
    const int total = B_ * H * W;
    const int Cin = Cin1 + Cin2;
    const int pixBase = blockIdx.x * 64 + wave * 16;
    const int coBase = blockIdx.y * 64;
    const int row = lane & 15;
    const int quad = lane >> 4;

    int P = pixBase + row;
    bool pv = P < total;
    int Pc = pv ? P : 0;
    int pb = Pc / (H * W);
    int r0i = Pc - pb * (H * W);
    int ph = r0i / W;
    int pw = r0i - ph * W;

    floatx4 acc[4];
#pragma unroll
    for (int i = 0; i < 4; i++) acc[i] = (floatx4){0.f, 0.f, 0.f, 0.f};
    const short8 zero8 = {0, 0, 0, 0, 0, 0, 0, 0};

    for (int tap = 0; tap < 9; tap++) {
        int kh = tap / 3, kw = tap - kh * 3;
        int ih = ph + kh - 1, iw = pw + kw - 1;
        bool tv = pv && ((unsigned)ih < (unsigned)H) && ((unsigned)iw < (unsigned)W);
        // source 1
        {
            size_t ab = ((size_t)(pb * H + ih) * W + iw) * (size_t)Cin1 + quad * 8;
            const unsigned short* __restrict__ wrow =
                wTsq + (size_t)(tap * Cout + coBase) * Cin + quad * 8;
            for (int kb = 0; kb < Cin1; kb += 32) {
                short8 ah = zero8, al = zero8;
                if (tv) {
                    ah = *(const short8*)(s1h + ab + kb);
                    al = *(const short8*)(s1l + ab + kb);
                }
#pragma unroll
                for (int nt = 0; nt < 4; nt++) {
                    short8 bf = *(const short8*)(wrow + (size_t)(nt * 16 + row) * Cin + kb);
                    acc[nt] = __builtin_amdgcn_mfma_f32_16x16x32_bf16(ah, bf, acc[nt], 0, 0, 0);
                    acc[nt] = __builtin_amdgcn_mfma_f32_16x16x32_bf16(al, bf, acc[nt], 0, 0, 0);
                }
            }
        }
        // source 2 (fused skip concat)
        if (Cin2 > 0) {
            size_t ab = ((size_t)(pb * H2 + ih + dh) * W2 + (iw + dw)) * (size_t)Cin2 + quad * 8;
            const unsigned short* __restrict__ wrow =
                wTsq + (size_t)(tap * Cout + coBase) * Cin + Cin1 + quad * 8;
            for (int kb = 0; kb < Cin2; kb += 32) {
                short8 ah = zero8, al = zero8;
                if (tv) {
                    ah = *(const short8*)(s2h + ab + kb);
                    al = *(const short8*)(s2l + ab + kb);
                }
#pragma unroll
                for (int nt = 0; nt < 4; nt++) {
                    short8 bf = *(const short8*)(wrow + (size_t)(nt * 16 + row) * Cin + kb);
                    acc[nt] = __builtin_amdgcn_mfma_f32_16x16x32_bf16(ah, bf, acc[nt], 0, 0, 0);
                    acc[nt] = __builtin_amdgcn_mfma_f32_16x16x32_bf16(al, bf, acc[nt], 0, 0, 0);
                }
            }
        }
    }

    // epilogue: D layout col(lane&15)=co, row(quad*4+r)=pixel
#pragma unroll
    for (int nt = 0; nt < 4; nt++) {
        int co = coBase + nt * 16 + row;
        float spv = spv_[co];
        floatx4 a = acc[nt];
#pragma unroll
        for (int r = 0; r < 4; r++) {
            int P2 = pixBase + quad * 4 + r;
            if (P2 < total) {
                size_t o = (size_t)P2 * Cout + co;
                float g = muG[o];
                float s = (g > 0.f) ? (q9v[P2] * spv + a[r]) : 0.f;
                if (outF) outF[o] = s;
                if (outH) {
                    unsigned short hh = f2bf(s);
                    outH[o] = hh;
                    outL[o] = f2bf(s - bfval(hh));
                }
            }
        }
    }
}

// ---- first layer (Cin=3): mu fp32 + s hi/lo
__global__ void conv_input_relu_kernel(const float* __restrict__ x,
                                       const float* __restrict__ w_mu,
                                       const float* __restrict__ w_sig,
                                       float* __restrict__ mu_out,
                                       unsigned short* __restrict__ s_hi,
                                       unsigned short* __restrict__ s_lo,
                                       int B_, int H, int W, int Cin, int Cout)
{
    int co = threadIdx.x;
    int pix = blockIdx.x * blockDim.y + threadIdx.y;
    int total = B_ * H * W;
    if (pix >= total) return;
    int b = pix / (H * W);
    int rem = pix % (H * W);
    int h = rem / W, w = rem % W;

    float mu = 0.f, q = 0.f;
    for (int kh = 0; kh < 3; kh++) {
        int ih = h + kh - 1;
        if (ih < 0 || ih >= H) continue;
        for (int kw = 0; kw < 3; kw++) {
            int iw = w + kw - 1;
            if (iw < 0 || iw >= W) continue;
            const float* xp = x + ((size_t)(b * H + ih) * W + iw) * Cin;
            const float* wp = w_mu + (size_t)((kh * 3 + kw) * Cin) * Cout + co;
            for (int ci = 0; ci < Cin; ci++) {
                float xv = xp[ci];
                mu += xv * wp[(size_t)ci * Cout];
                q += xv * xv;
            }
        }
    }
    float s = q * softplus_f(w_sig[co]);
    if (!(mu > 0.f)) { mu = 0.f; s = 0.f; }
    size_t oidx = (size_t)pix * Cout + co;
    mu_out[oidx] = mu;
    unsigned short hh = f2bf(s);
    s_hi[oidx] = hh;
    s_lo[oidx] = f2bf(s - bfval(hh));
}

// ---- unpool+conv (fp32 vector, in-register w^2, tq precomputed):
// mu out fp32 (relu'd), s out hi/lo bf16
__global__ void __launch_bounds__(256)
conv_unpool_fused(const float* __restrict__ mu_in,
                  const float* __restrict__ s_in,
                  const float* __restrict__ tq,
                  const float* __restrict__ w_mu,
                  const float* __restrict__ w_sig,
                  float* __restrict__ mu_out,
                  unsigned short* __restrict__ s_hi,
                  unsigned short* __restrict__ s_lo,
                  int B_, int Hin, int Win, int Cin,
                  int Hout, int Wout, int Cout)
{
    int cog = threadIdx.x * 4;
    int pix = blockIdx.x * blockDim.y + threadIdx.y;
    int total = B_ * Hout * Wout;
    if (pix >= total) return;
    int b = pix / (Hout * Wout);
    int rem = pix - b * (Hout * Wout);
    int ho = rem / Wout, wo = rem - (rem / Wout) * Wout;

    int khs[2], ihs[2], nkh;
    if (ho & 1) { nkh = 2; khs[0] = 0; ihs[0] = (ho - 1) >> 1; khs[1] = 2; ihs[1] = (ho + 1) >> 1; }
    else        { nkh = 1; khs[0] = 1; ihs[0] = ho >> 1; }
    int kws[2], iws[2], nkw;
    if (wo & 1) { nkw = 2; kws[0] = 0; iws[0] = (wo - 1) >> 1; kws[1] = 2; iws[1] = (wo + 1) >> 1; }
    else        { nkw = 1; kws[0] = 1; iws[0] = wo >> 1; }

    float4 amu = make_float4(0.f, 0.f, 0.f, 0.f);
    float4 asa = make_float4(0.f, 0.f, 0.f, 0.f);
    float q = 0.f;

    for (int a = 0; a < nkh; a++) {
        for (int c = 0; c < nkw; c++) {
            q += tq[(size_t)(b * Hin + ihs[a]) * Win + iws[c]];
            size_t base = ((size_t)(b * Hin + ihs[a]) * Win + iws[c]) * Cin;
            const float* mp = mu_in + base;
            const float* sp = s_in + base;
            const float* wp = w_mu + (size_t)((khs[a] * 3 + kws[c]) * Cin) * Cout + cog;
            for (int ci = 0; ci < Cin; ci += 4) {
                float4 m4 = *(const float4*)(mp + ci);
                float4 s4 = *(const float4*)(sp + ci);
                const float* wb = wp + (size_t)ci * Cout;
                float4 w0 = *(const float4*)(wb);
                float4 w1 = *(const float4*)(wb + Cout);
                float4 w2 = *(const float4*)(wb + 2 * Cout);
                float4 w3 = *(const float4*)(wb + 3 * Cout);
                amu.x += m4.x*w0.x + m4.y*w1.x + m4.z*w2.x + m4.w*w3.x;
                amu.y += m4.x*w0.y + m4.y*w1.y + m4.z*w2.y + m4.w*w3.y;
                amu.z += m4.x*w0.z + m4.y*w1.z + m4.z*w2.z + m4.w*w3.z;
                amu.w += m4.x*w0.w + m4.y*w1.w + m4.z*w2.w + m4.w*w3.w;
                asa.x += s4.x*(w0.x*w0.x) + s4.y*(w1.x*w1.x) + s4.z*(w2.x*w2.x) + s4.w*(w3.x*w3.x);
                asa.y += s4.x*(w0.y*w0.y) + s4.y*(w1.y*w1.y) + s4.z*(w2.y*w2.y) + s4.w*(w3.y*w3.y);
                asa.z += s4.x*(w0.z*w0.z) + s4.y*(w1.z*w1.z) + s4.z*(w2.z*w2.z) + s4.w*(w3.z*w3.z);
                asa.w += s4.x*(w0.w*w0.w) + s4.y*(w1.w*w1.w) + s4.z*(w2.w*w2.w) + s4.w*(w3.w*w3.w);
            }
        }
    }
    float4 sg = *(const float4*)(w_sig + cog);
    float4 so;
    so.x = q * softplus_f(sg.x) + asa.x;
    so.y = q * softplus_f(sg.y) + asa.y;
    so.z = q * softplus_f(sg.z) + asa.z;
    so.w = q * softplus_f(sg.w) + asa.w;
    if (!(amu.x > 0.f)) { amu.x = 0.f; so.x = 0.f; }
    if (!(amu.y > 0.f)) { amu.y = 0.f; so.y = 0.f; }
    if (!(amu.z > 0.f)) { amu.z = 0.f; so.z = 0.f; }
    if (!(amu.w > 0.f)) { amu.w = 0.f; so.w = 0.f; }
    size_t oidx = (size_t)pix * Cout + cog;
    *(float4*)(mu_out + oidx) = amu;
    unsigned short h0 = f2bf(so.x), h1 = f2bf(so.y), h2 = f2bf(so.z), h3 = f2bf(so.w);
    s_hi[oidx] = h0; s_hi[oidx + 1] = h1; s_hi[oidx + 2] = h2; s_hi[oidx + 3] = h3;
    s_lo[oidx]     = f2bf(so.x - bfval(h0));
    s_lo[oidx + 1] = f2bf(so.y - bfval(h1));
    s_lo[oidx + 2] = f2bf(so.z - bfval(h2));
    s_lo[oidx + 3] = f2bf(so.w - bfval(h3));
}

// ---- pool: mu fp32, s hi/lo gather at argmax
__global__ void pool_kernel(const float* __restrict__ mu_in,
                            const unsigned short* __restrict__ s_h,
                            const unsigned short* __restrict__ s_l,
                            float* __restrict__ mu_out,
                            unsigned short* __restrict__ so_h,
                            unsigned short* __restrict__ so_l,
                            int B_, int H, int W, int C)
{
    int Ho = H / 2, Wo = W / 2;
    size_t total = (size_t)B_ * Ho * Wo * C;
    size_t idx = (size_t)blockIdx.x * blockDim.x + threadIdx.x;
    if (idx >= total) return;
    int c = idx % C;
    size_t t = idx / C;
    int w = t % Wo; t /= Wo;
    int h = t % Ho;
    int b = t / Ho;
    size_t i0 = ((size_t)(b * H + 2 * h) * W + 2 * w) * C + c;
    size_t rowStride = (size_t)W * C;
    float m00 = mu_in[i0], m01 = mu_in[i0 + C];
    float m10 = mu_in[i0 + rowStride], m11 = mu_in[i0 + rowStride + C];
    int best = 0; float bm = m00;
    if (m01 > bm) { bm = m01; best = 1; }
    if (m10 > bm) { bm = m10; best = 2; }
    if (m11 > bm) { bm = m11; best = 3; }
    size_t off = (size_t)(best >> 1) * rowStride + (size_t)(best & 1) * C;
    mu_out[idx] = bm;
    so_h[idx] = s_h[i0 + off];
    so_l[idx] = s_l[i0 + off];
}

// ---- final 1x1 conv_inter + C=2 softmax density prop (fp32 in)
__global__ void final_kernel(const float* __restrict__ mu_in,
                             const float* __restrict__ s_in,
                             const float* __restrict__ w_mu,
                             const float* __restrict__ w_sig,
                             float* __restrict__ out,
                             int B_, int H, int W, int Cin)
{
    int pix = blockIdx.x * blockDim.x + threadIdx.x;
    int total = B_ * H * W;
    if (pix >= total) return;
    const float* mp = mu_in + (size_t)pix * Cin;
    const float* sp = s_in + (size_t)pix * Cin;
    float mu0 = 0.f, mu1 = 0.f, s0a = 0.f, s1a = 0.f, q = 0.f;
    for (int ci = 0; ci < Cin; ci += 4) {
        float4 m = *(const float4*)(mp + ci);
        float4 s = *(const float4*)(sp + ci);
        float4 wa = *(const float4*)(w_mu + ci * 2);
        float4 wb = *(const float4*)(w_mu + ci * 2 + 4);
        mu0 += m.x * wa.x + m.y * wa.z + m.z * wb.x + m.w * wb.z;
        mu1 += m.x * wa.y + m.y * wa.w + m.z * wb.y + m.w * wb.w;
        s0a += s.x * (wa.x * wa.x) + s.y * (wa.z * wa.z) + s.z * (wb.x * wb.x) + s.w * (wb.z * wb.z);
        s1a += s.x * (wa.y * wa.y) + s.y * (wa.w * wa.w) + s.z * (wb.y * wb.y) + s.w * (wb.w * wb.w);
        q += m.x * m.x + s.x + m.y * m.y + s.y + m.z * m.z + s.z + m.w * m.w + s.w;
    }
    float s0 = q * softplus_f(w_sig[0]) + s0a;
    float s1 = q * softplus_f(w_sig[1]) + s1a;
    float mx = fmaxf(mu0, mu1);
    float e0 = expf(mu0 - mx), e1 = expf(mu1 - mx);
    float inv = 1.f / (e0 + e1);
    float p0 = e0 * inv, p1 = e1 * inv;
    float g00 = p0 - p0 * p0, g01 = -p0 * p1;
    float g10 = -p1 * p0,     g11 = p1 - p1 * p1;
    float so0 = g00 * g00 * s0 + g01 * g01 * s1;
    float so1 = g10 * g10 * s0 + g11 * g11 * s1;
    out[(size_t)pix * 2]     = p0;
    out[(size_t)pix * 2 + 1] = p1;
    size_t off = (size_t)total * 2;
    out[off + (size_t)pix * 2]     = so0;
    out[off + (size_t)pix * 2 + 1] = so1;
}

// ---------------------------------------------------------------------------

extern "C" void kernel_launch(void* const* d_in, const int* in_sizes, int n_in,
                              void* d_out, int out_size, void* d_ws, size_t ws_size,
                              hipStream_t stream)
{
    const float* x = (const float*)d_in[0];
    enum { E1A, E1B, E2A, E2B, BA, BB, D2U, D2A, D2B, D1U, D1A, D1B, FIN, NW };
    const float* wmu[NW];
    const float* wsig[NW];
    for (int i = 0; i < NW; i++) {
        wmu[i]  = (const float*)d_in[1 + 2 * i];
        wsig[i] = (const float*)d_in[2 + 2 * i];
    }

    const int B_ = 4;
    float* ws = (float*)d_ws;
    float* M0   = ws;                        // 4194304
    float* M1   = ws + 4194304;              // 4194304
    float* E1mu = ws + 8388608;              // 4194304
    float* E2mu = ws + 12582912;             // 2097152
    float* SF   = ws + 14680064;             // 4194304 (fp32 s where needed)
    float* tq   = ws + 18874368;             // 65536
    float* q9   = ws + 18939904;             // 65536
    float* spb  = ws + 19005440;             // 2048
    unsigned short* us = (unsigned short*)(ws + 19007488);
    unsigned short* bS0h  = us;              // 4194304 each
    unsigned short* bS0l  = us + 4194304;
    unsigned short* bS1h  = us + 8388608;
    unsigned short* bS1l  = us + 12582912;
    unsigned short* bE1sh = us + 16777216;
    unsigned short* bE1sl = us + 20971520;
    unsigned short* bE2sh = us + 25165824;   // 2097152 each
    unsigned short* bE2sl = us + 27262976;
    unsigned short* wTsq  = us + 29360128;   // 1695744

    // MFMA layer table
    const int mlay[9]  = {E1B, E2A, E2B, BA, BB, D2A, D2B, D1A, D1B};
    const int mcin[9]  = {64, 64, 128, 128, 256, 256, 128, 128, 64};
    const int mcout[9] = {64, 128, 128, 256, 256, 128, 128, 64, 64};
    size_t woff[NW]; int spoff[NW];
    {
        size_t wo = 0; int so = 0;
        for (int i = 0; i < 9; i++) {
            int l = mlay[i];
            woff[l] = wo; spoff[l] = so;
            int n = 9 * mcin[i] * mcout[i];
            wprep_kernel<<<dim3((n + 255) / 256), dim3(256), 0, stream>>>(
                wmu[l], wTsq + wo, mcin[i], mcout[i], n);
            sp_kernel<<<dim3(1), dim3(256), 0, stream>>>(wsig[l], spb + so, mcout[i]);
            wo += n; so += mcout[i];
        }
    }

    // full hybrid layer: t/q9 + mu vector conv + s MFMA
    auto layer = [&](const float* muIn, const unsigned short* sInH, const unsigned short* sInL,
                     int ci1,
                     const float* skMu, const unsigned short* skSH, const unsigned short* skSL,
                     int ci2, int h2, int w2, int dh, int dw,
                     int H, int W, int widx, int cout,
                     float* muOut, unsigned short* oH, unsigned short* oL, float* oF) {
        int total = B_ * H * W;
        t_mixed_kernel<<<dim3((total + 255) / 256), dim3(256), 0, stream>>>(
            muIn, sInH, sInL, skMu, skSH, skSL, tq, B_, H, W, ci1, ci2, h2, w2, dh, dw);
        q9_kernel<<<dim3((total + 255) / 256), dim3(256), 0, stream>>>(tq, q9, B_, H, W);
        int tx = cout / 8, ty = 256 / tx;
        muconv_kernel<<<dim3((total + ty - 1) / ty), dim3(tx, ty), 0, stream>>>(
            muIn, skMu, wmu[widx], muOut, B_, H, W, ci1, ci2, h2, w2, dh, dw, cout);
        smfma_kernel<<<dim3((total + 63) / 64, cout / 64), dim3(256), 0, stream>>>(
            sInH, sInL, skSH, skSL, q9, wTsq + woff[widx], spb + spoff[widx], muOut,
            oH, oL, oF, B_, H, W, ci1, ci2, h2, w2, dh, dw, cout);
    };

    auto unpool = [&](const float* mi, const float* si,
                      int hi, int wi, int ci, int ho, int wo, int co, int widx,
                      float* muOut, unsigned short* sH, unsigned short* sL) {
        int nin = B_ * hi * wi;
        t_f32_kernel<<<dim3((nin + 255) / 256), dim3(256), 0, stream>>>(mi, si, tq, nin, ci);
        int totalPix = B_ * ho * wo;
        int tx = co / 4, ty = 256 / tx;
        conv_unpool_fused<<<dim3((totalPix + ty - 1) / ty), dim3(tx, ty), 0, stream>>>(
            mi, si, tq, wmu[widx], wsig[widx], muOut, sH, sL,
            B_, hi, wi, ci, ho, wo, co);
    };

    // ---- encoder level 1 ----
    {
        int totalPix = B_ * 128 * 128;
        conv_input_relu_kernel<<<dim3((totalPix + 3) / 4), dim3(64, 4), 0, stream>>>(
            x, wmu[E1A], wsig[E1A], M0, bS0h, bS0l, B_, 128, 128, 3, 64);
    }
    layer(M0, bS0h, bS0l, 64, nullptr, nullptr, nullptr, 0, 0, 0, 0, 0,
          128, 128, E1B, 64, E1mu, bE1sh, bE1sl, nullptr);
    {
        size_t total = (size_t)B_ * 64 * 64 * 64;
        pool_kernel<<<dim3((total + 255) / 256), dim3(256), 0, stream>>>(
            E1mu, bE1sh, bE1sl, M0, bS0h, bS0l, B_, 128, 128, 64);
    }
    // ---- encoder level 2 ----
    layer(M0, bS0h, bS0l, 64, nullptr, nullptr, nullptr, 0, 0, 0, 0, 0,
          64, 64, E2A, 128, M1, bS1h, bS1l, nullptr);
    layer(M1, bS1h, bS1l, 128, nullptr, nullptr, nullptr, 0, 0, 0, 0, 0,
          64, 64, E2B, 128, E2mu, bE2sh, bE2sl, nullptr);
    {
        size_t total = (size_t)B_ * 32 * 32 * 128;
        pool_kernel<<<dim3((total + 255) / 256), dim3(256), 0, stream>>>(
            E2mu, bE2sh, bE2sl, M0, bS0h, bS0l, B_, 64, 64, 128);
    }
    // ---- bottleneck ----
    layer(M0, bS0h, bS0l, 128, nullptr, nullptr, nullptr, 0, 0, 0, 0, 0,
          32, 32, BA, 256, M1, bS1h, bS1l, nullptr);
    layer(M1, bS1h, bS1l, 256, nullptr, nullptr, nullptr, 0, 0, 0, 0, 0,
          32, 32, BB, 256, M0, nullptr, nullptr, SF);
    // ---- decoder level 2 ----
    unpool(M0, SF, 32, 32, 256, 63, 63, 128, D2U, M1, bS1h, bS1l);
    layer(M1, bS1h, bS1l, 128, E2mu, bE2sh, bE2sl, 128, 64, 64, 0, 0,
          63, 63, D2A, 128, M0, bS0h, bS0l, nullptr);
    layer(M0, bS0h, bS0l, 128, nullptr, nullptr, nullptr, 0, 0, 0, 0, 0,
          63, 63, D2B, 128, M1, nullptr, nullptr, SF);
    // ---- decoder level 1 ----
    unpool(M1, SF, 63, 63, 128, 125, 125, 64, D1U, M0, bS0h, bS0l);
    layer(M0, bS0h, bS0l, 64, E1mu, bE1sh, bE1sl, 64, 128, 128, 1, 1,
          125, 125, D1A, 64, M1, bS1h, bS1l, nullptr);
    layer(M1, bS1h, bS1l, 64, nullptr, nullptr, nullptr, 0, 0, 0, 0, 0,
          125, 125, D1B, 64, M0, nullptr, nullptr, SF);
    // ---- final 1x1 + softmax prop ----
    {
        int totalPix = B_ * 125 * 125;
        final_kernel<<<dim3((totalPix + 63) / 64), dim3(64), 0, stream>>>(
            M0, SF, wmu[FIN], wsig[FIN], (float*)d_out, B_, 125, 125, 64);
    }
}

// Round 7
// 3707.057 us; speedup vs baseline: 2.1767x; 1.2581x over previous
//
#include <hip/hip_runtime.h>
#include <math.h>

// ---------------------------------------------------------------------------
// Variance-propagating UNet (density prop), NHWC.
// Round 6->7: keep hybrid (fp32 vector mu-chain for exact relu gates, bf16
// hi+lo MFMA s-conv). muconv now processes 2 W-adjacent pixels per thread:
// weight loads shared across the pair (10 VMEM / 64 FMA instead of 9/32).
// ---------------------------------------------------------------------------

typedef __attribute__((ext_vector_type(8))) short short8;
typedef __attribute__((ext_vector_type(4))) float floatx4;

__device__ __forceinline__ float softplus_f(float x) { return log1pf(expf(x)); }

__device__ __forceinline__ unsigned short f2bf(float x) {
    unsigned int u = __float_as_uint(x);
    u = (u + 0x7FFF + ((u >> 16) & 1)) >> 16;
    return (unsigned short)u;
}
__device__ __forceinline__ float bfval(unsigned short h) {
    return __uint_as_float((unsigned int)h << 16);
}
__device__ __forceinline__ float bf2f_lo(unsigned int u) {
    return __uint_as_float(u << 16);
}
__device__ __forceinline__ float bf2f_hi(unsigned int u) {
    return __uint_as_float(u & 0xFFFF0000u);
}

// ---- weight prep: wTsq[tap][co][ci] = bf16(w[tap][ci][co]^2)
__global__ void wprep_kernel(const float* __restrict__ w,
                             unsigned short* __restrict__ wTsq,
                             int Cin, int Cout, int n)
{
    int idx = blockIdx.x * blockDim.x + threadIdx.x;
    if (idx >= n) return;
    int per = Cin * Cout;
    int tap = idx / per;
    int rem = idx - tap * per;
    int co = rem / Cin;
    int ci = rem - co * Cin;
    float v = w[(size_t)(tap * Cin + ci) * Cout + co];
    wTsq[idx] = f2bf(v * v);
}

__global__ void sp_kernel(const float* __restrict__ wsig,
                          float* __restrict__ sp, int n)
{
    int i = blockIdx.x * blockDim.x + threadIdx.x;
    if (i < n) sp[i] = softplus_f(wsig[i]);
}

// ---- t from fp32 mu + hi/lo bf16 s (optional 2nd source at crop offset)
__global__ void t_mixed_kernel(const float* __restrict__ mu1,
                               const unsigned short* __restrict__ s1h,
                               const unsigned short* __restrict__ s1l,
                               const float* __restrict__ mu2,
                               const unsigned short* __restrict__ s2h,
                               const unsigned short* __restrict__ s2l,
                               float* __restrict__ t_out,
                               int B_, int Hin, int Win, int Cin1, int Cin2,
                               int H2, int W2, int dh, int dw)
{
    int pix = blockIdx.x * blockDim.x + threadIdx.x;
    int total = B_ * Hin * Win;
    if (pix >= total) return;
    float acc = 0.f;
    {
        const float* mp = mu1 + (size_t)pix * Cin1;
        const unsigned short* sh = s1h + (size_t)pix * Cin1;
        const unsigned short* sl = s1l + (size_t)pix * Cin1;
        for (int ci = 0; ci < Cin1; ci += 8) {
            float4 m0 = *(const float4*)(mp + ci);
            float4 m1 = *(const float4*)(mp + ci + 4);
            uint4 vh = *(const uint4*)(sh + ci);
            uint4 vl = *(const uint4*)(sl + ci);
            acc += m0.x*m0.x + m0.y*m0.y + m0.z*m0.z + m0.w*m0.w
                 + m1.x*m1.x + m1.y*m1.y + m1.z*m1.z + m1.w*m1.w;
            acc += bf2f_lo(vh.x) + bf2f_hi(vh.x) + bf2f_lo(vh.y) + bf2f_hi(vh.y)
                 + bf2f_lo(vh.z) + bf2f_hi(vh.z) + bf2f_lo(vh.w) + bf2f_hi(vh.w);
            acc += bf2f_lo(vl.x) + bf2f_hi(vl.x) + bf2f_lo(vl.y) + bf2f_hi(vl.y)
                 + bf2f_lo(vl.z) + bf2f_hi(vl.z) + bf2f_lo(vl.w) + bf2f_hi(vl.w);
        }
    }
    if (Cin2 > 0) {
        int b = pix / (Hin * Win);
        int rem = pix - b * (Hin * Win);
        int h = rem / Win, w = rem - (rem / Win) * Win;
        size_t base = ((size_t)(b * H2 + h + dh) * W2 + (w + dw)) * Cin2;
        const float* mp = mu2 + base;
        const unsigned short* sh = s2h + base;
        const unsigned short* sl = s2l + base;
        for (int ci = 0; ci < Cin2; ci += 8) {
            float4 m0 = *(const float4*)(mp + ci);
            float4 m1 = *(const float4*)(mp + ci + 4);
            uint4 vh = *(const uint4*)(sh + ci);
            uint4 vl = *(const uint4*)(sl + ci);
            acc += m0.x*m0.x + m0.y*m0.y + m0.z*m0.z + m0.w*m0.w
                 + m1.x*m1.x + m1.y*m1.y + m1.z*m1.z + m1.w*m1.w;
            acc += bf2f_lo(vh.x) + bf2f_hi(vh.x) + bf2f_lo(vh.y) + bf2f_hi(vh.y)
                 + bf2f_lo(vh.z) + bf2f_hi(vh.z) + bf2f_lo(vh.w) + bf2f_hi(vh.w);
            acc += bf2f_lo(vl.x) + bf2f_hi(vl.x) + bf2f_lo(vl.y) + bf2f_hi(vl.y)
                 + bf2f_lo(vl.z) + bf2f_hi(vl.z) + bf2f_lo(vl.w) + bf2f_hi(vl.w);
        }
    }
    t_out[pix] = acc;
}

// ---- t from fp32 mu + fp32 s (for unpool-conv inputs)
__global__ void t_f32_kernel(const float* __restrict__ mu1, const float* __restrict__ s1,
                             float* __restrict__ t_out, int total, int Cin)
{
    int pix = blockIdx.x * blockDim.x + threadIdx.x;
    if (pix >= total) return;
    const float* mp = mu1 + (size_t)pix * Cin;
    const float* sp = s1 + (size_t)pix * Cin;
    float acc = 0.f;
    for (int ci = 0; ci < Cin; ci += 4) {
        float4 m = *(const float4*)(mp + ci);
        float4 s = *(const float4*)(sp + ci);
        acc += m.x * m.x + s.x + m.y * m.y + s.y
             + m.z * m.z + s.z + m.w * m.w + s.w;
    }
    t_out[pix] = acc;
}

// ---- q9: sum t over valid 3x3 taps (pad=1)
__global__ void q9_kernel(const float* __restrict__ t_in,
                          float* __restrict__ q9, int B_, int H, int W)
{
    int pix = blockIdx.x * blockDim.x + threadIdx.x;
    int total = B_ * H * W;
    if (pix >= total) return;
    int b = pix / (H * W);
    int rem = pix - b * (H * W);
    int h = rem / W, w = rem - (rem / W) * W;
    float acc = 0.f;
    for (int kh = 0; kh < 3; kh++) {
        int ih = h + kh - 1;
        if ((unsigned)ih >= (unsigned)H) continue;
        for (int kw = 0; kw < 3; kw++) {
            int iw = w + kw - 1;
            if ((unsigned)iw >= (unsigned)W) continue;
            acc += t_in[(size_t)(b * H + ih) * W + iw];
        }
    }
    q9[pix] = acc;
}

// ---- mu conv: fp32 vector, 8 cout x 2 W-adjacent pixels per thread.
// Weight loads shared across the pixel pair. Relu'd fp32 output (the gate).
__global__ void __launch_bounds__(256)
muconv_kernel(const float* __restrict__ mu1, const float* __restrict__ mu2,
              const float* __restrict__ w_mu,
              float* __restrict__ mu_out,
              int B_, int H, int W, int Cin1, int Cin2,
              int H2, int W2, int dh, int dw, int Cout)
{
    const int cog = threadIdx.x * 8;
    const int Wp = (W + 1) >> 1;
    int pr = blockIdx.x * blockDim.y + threadIdx.y;
    int totalP = B_ * H * Wp;
    if (pr >= totalP) return;
    int b = pr / (H * Wp);
    int rem = pr - b * (H * Wp);
    int h = rem / Wp;
    int w0 = (rem - h * Wp) << 1;
    const bool pex1 = (w0 + 1) < W;
    const int Cin = Cin1 + Cin2;

    float acc0[8], acc1[8];
#pragma unroll
    for (int i = 0; i < 8; i++) { acc0[i] = 0.f; acc1[i] = 0.f; }

    for (int kh = 0; kh < 3; kh++) {
        int ih = h + kh - 1;
        if ((unsigned)ih >= (unsigned)H) continue;
        for (int kw = 0; kw < 3; kw++) {
            int iw0 = w0 + kw - 1;
            int iw1 = iw0 + 1;
            bool v0 = (unsigned)iw0 < (unsigned)W;
            bool v1 = pex1 && ((unsigned)iw1 < (unsigned)W);
            if (!v0 && !v1) continue;
            const float* __restrict__ wp =
                w_mu + (size_t)((kh * 3 + kw) * Cin) * Cout + cog;
            // ---- source 1 ----
            {
                const float* rowb = mu1 + (size_t)(b * H + ih) * W * Cin1;
                if (v0 && v1) {
                    const float* mp0 = rowb + (size_t)iw0 * Cin1;
                    const float* mp1 = rowb + (size_t)iw1 * Cin1;
                    for (int ci = 0; ci < Cin1; ci += 4) {
                        const float* wb = wp + (size_t)ci * Cout;
                        float4 a0 = *(const float4*)(wb);
                        float4 a1 = *(const float4*)(wb + 4);
                        float4 b0 = *(const float4*)(wb + Cout);
                        float4 b1 = *(const float4*)(wb + Cout + 4);
                        float4 c0 = *(const float4*)(wb + 2 * Cout);
                        float4 c1 = *(const float4*)(wb + 2 * Cout + 4);
                        float4 d0 = *(const float4*)(wb + 3 * Cout);
                        float4 d1 = *(const float4*)(wb + 3 * Cout + 4);
                        float4 m0 = *(const float4*)(mp0 + ci);
                        float4 m1 = *(const float4*)(mp1 + ci);
                        acc0[0] += m0.x*a0.x + m0.y*b0.x + m0.z*c0.x + m0.w*d0.x;
                        acc0[1] += m0.x*a0.y + m0.y*b0.y + m0.z*c0.y + m0.w*d0.y;
                        acc0[2] += m0.x*a0.z + m0.y*b0.z + m0.z*c0.z + m0.w*d0.z;
                        acc0[3] += m0.x*a0.w + m0.y*b0.w + m0.z*c0.w + m0.w*d0.w;
                        acc0[4] += m0.x*a1.x + m0.y*b1.x + m0.z*c1.x + m0.w*d1.x;
                        acc0[5] += m0.x*a1.y + m0.y*b1.y + m0.z*c1.y + m0.w*d1.y;
                        acc0[6] += m0.x*a1.z + m0.y*b1.z + m0.z*c1.z + m0.w*d1.z;
                        acc0[7] += m0.x*a1.w + m0.y*b1.w + m0.z*c1.w + m0.w*d1.w;
                        acc1[0] += m1.x*a0.x + m1.y*b0.x + m1.z*c0.x + m1.w*d0.x;
                        acc1[1] += m1.x*a0.y + m1.y*b0.y + m1.z*c0.y + m1.w*d0.y;
                        acc1[2] += m1.x*a0.z + m1.y*b0.z + m1.z*c0.z + m1.w*d0.z;
                        acc1[3] += m1.x*a0.w + m1.y*b0.w + m1.z*c0.w + m1.w*d0.w;
                        acc1[4] += m1.x*a1.x + m1.y*b1.x + m1.z*c1.x + m1.w*d1.x;
                        acc1[5] += m1.x*a1.y + m1.y*b1.y + m1.z*c1.y + m1.w*d1.y;
                        acc1[6] += m1.x*a1.z + m1.y*b1.z + m1.z*c1.z + m1.w*d1.z;
                        acc1[7] += m1.x*a1.w + m1.y*b1.w + m1.z*c1.w + m1.w*d1.w;
                    }
                } else {
                    const float* mp = rowb + (size_t)(v0 ? iw0 : iw1) * Cin1;
                    float* ac = v0 ? acc0 : acc1;
                    for (int ci = 0; ci < Cin1; ci += 4) {
                        const float* wb = wp + (size_t)ci * Cout;
                        float4 a0 = *(const float4*)(wb);
                        float4 a1 = *(const float4*)(wb + 4);
                        float4 b0 = *(const float4*)(wb + Cout);
                        float4 b1 = *(const float4*)(wb + Cout + 4);
                        float4 c0 = *(const float4*)(wb + 2 * Cout);
                        float4 c1 = *(const float4*)(wb + 2 * Cout + 4);
                        float4 d0 = *(const float4*)(wb + 3 * Cout);
                        float4 d1 = *(const float4*)(wb + 3 * Cout + 4);
                        float4 m0 = *(const float4*)(mp + ci);
                        ac[0] += m0.x*a0.x + m0.y*b0.x + m0.z*c0.x + m0.w*d0.x;
                        ac[1] += m0.x*a0.y + m0.y*b0.y + m0.z*c0.y + m0.w*d0.y;
                        ac[2] += m0.x*a0.z + m0.y*b0.z + m0.z*c0.z + m0.w*d0.z;
                        ac[3] += m0.x*a0.w + m0.y*b0.w + m0.z*c0.w + m0.w*d0.w;
                        ac[4] += m0.x*a1.x + m0.y*b1.x + m0.z*c1.x + m0.w*d1.x;
                        ac[5] += m0.x*a1.y + m0.y*b1.y + m0.z*c1.y + m0.w*d1.y;
                        ac[6] += m0.x*a1.z + m0.y*b1.z + m0.z*c1.z + m0.w*d1.z;
                        ac[7] += m0.x*a1.w + m0.y*b1.w + m0.z*c1.w + m0.w*d1.w;
                    }
                }
            }
            // ---- source 2 (fused skip concat) ----
            if (Cin2 > 0) {
                const float* rowb = mu2 + (size_t)(b * H2 + ih + dh) * W2 * Cin2;
                const float* __restrict__ wp2 = wp + (size_t)Cin1 * Cout;
                if (v0 && v1) {
                    const float* mp0 = rowb + (size_t)(iw0 + dw) * Cin2;
                    const float* mp1 = rowb + (size_t)(iw1 + dw) * Cin2;
                    for (int ci = 0; ci < Cin2; ci += 4) {
                        const float* wb = wp2 + (size_t)ci * Cout;
                        float4 a0 = *(const float4*)(wb);
                        float4 a1 = *(const float4*)(wb + 4);
                        float4 b0 = *(const float4*)(wb + Cout);
                        float4 b1 = *(const float4*)(wb + Cout + 4);
                        float4 c0 = *(const float4*)(wb + 2 * Cout);
                        float4 c1 = *(const float4*)(wb + 2 * Cout + 4);
                        float4 d0 = *(const float4*)(wb + 3 * Cout);
                        float4 d1 = *(const float4*)(wb + 3 * Cout + 4);
                        float4 m0 = *(const float4*)(mp0 + ci);
                        float4 m1 = *(const float4*)(mp1 + ci);
                        acc0[0] += m0.x*a0.x + m0.y*b0.x + m0.z*c0.x + m0.w*d0.x;
                        acc0[1] += m0.x*a0.y + m0.y*b0.y + m0.z*c0.y + m0.w*d0.y;
                        acc0[2] += m0.x*a0.z + m0.y*b0.z + m0.z*c0.z + m0.w*d0.z;
                        acc0[3] += m0.x*a0.w + m0.y*b0.w + m0.z*c0.w + m0.w*d0.w;
                        acc0[4] += m0.x*a1.x + m0.y*b1.x + m0.z*c1.x + m0.w*d1.x;
                        acc0[5] += m0.x*a1.y + m0.y*b1.y + m0.z*c1.y + m0.w*d1.y;
                        acc0[6] += m0.x*a1.z + m0.y*b1.z + m0.z*c1.z + m0.w*d1.z;
                        acc0[7] += m0.x*a1.w + m0.y*b1.w + m0.z*c1.w + m0.w*d1.w;
                        acc1[0] += m1.x*a0.x + m1.y*b0.x + m1.z*c0.x + m1.w*d0.x;
                        acc1[1] += m1.x*a0.y + m1.y*b0.y + m1.z*c0.y + m1.w*d0.y;
                        acc1[2] += m1.x*a0.z + m1.y*b0.z + m1.z*c0.z + m1.w*d0.z;
                        acc1[3] += m1.x*a0.w + m1.y*b0.w + m1.z*c0.w + m1.w*d0.w;
                        acc1[4] += m1.x*a1.x + m1.y*b1.x + m1.z*c1.x + m1.w*d1.x;
                        acc1[5] += m1.x*a1.y + m1.y*b1.y + m1.z*c1.y + m1.w*d1.y;
                        acc1[6] += m1.x*a1.z + m1.y*b1.z + m1.z*c1.z + m1.w*d1.z;
                        acc1[7] += m1.x*a1.w + m1.y*b1.w + m1.z*c1.w + m1.w*d1.w;
                    }
                } else {
                    const float* mp = rowb + (size_t)((v0 ? iw0 : iw1) + dw) * Cin2;
                    float* ac = v0 ? acc0 : acc1;
                    for (int ci = 0; ci < Cin2; ci += 4) {
                        const float* wb = wp2 + (size_t)ci * Cout;
                        float4 a0 = *(const float4*)(wb);
                        float4 a1 = *(const float4*)(wb + 4);
                        float4 b0 = *(const float4*)(wb + Cout);
                        float4 b1 = *(const float4*)(wb + Cout + 4);
                        float4 c0 = *(const float4*)(wb + 2 * Cout);
                        float4 c1 = *(const float4*)(wb + 2 * Cout + 4);
                        float4 d0 = *(const float4*)(wb + 3 * Cout);
                        float4 d1 = *(const float4*)(wb + 3 * Cout + 4);
                        float4 m0 = *(const float4*)(mp + ci);
                        ac[0] += m0.x*a0.x + m0.y*b0.x + m0.z*c0.x + m0.w*d0.x;
                        ac[1] += m0.x*a0.y + m0.y*b0.y + m0.z*c0.y + m0.w*d0.y;
                        ac[2] += m0.x*a0.z + m0.y*b0.z + m0.z*c0.z + m0.w*d0.z;
                        ac[3] += m0.x*a0.w + m0.y*b0.w + m0.z*c0.w + m0.w*d0.w;
                        ac[4] += m0.x*a1.x + m0.y*b1.x + m0.z*c1.x + m0.w*d1.x;
                        ac[5] += m0.x*a1.y + m0.y*b1.y + m0.z*c1.y + m0.w*d1.y;
                        ac[6] += m0.x*a1.z + m0.y*b1.z + m0.z*c1.z + m0.w*d1.z;
                        ac[7] += m0.x*a1.w + m0.y*b1.w + m0.z*c1.w + m0.w*d1.w;
                    }
                }
            }
        }
    }
    size_t pix0 = (size_t)(b * H + h) * W + w0;
    size_t o = pix0 * Cout + cog;
    float4 r0, r1;
    r0.x = fmaxf(acc0[0], 0.f); r0.y = fmaxf(acc0[1], 0.f);
    r0.z = fmaxf(acc0[2], 0.f); r0.w = fmaxf(acc0[3], 0.f);
    r1.x = fmaxf(acc0[4], 0.f); r1.y = fmaxf(acc0[5], 0.f);
    r1.z = fmaxf(acc0[6], 0.f); r1.w = fmaxf(acc0[7], 0.f);
    *(float4*)(mu_out + o) = r0;
    *(float4*)(mu_out + o + 4) = r1;
    if (pex1) {
        size_t o1 = o + Cout;
        float4 q0, q1;
        q0.x = fmaxf(acc1[0], 0.f); q0.y = fmaxf(acc1[1], 0.f);
        q0.z = fmaxf(acc1[2], 0.f); q0.w = fmaxf(acc1[3], 0.f);
        q1.x = fmaxf(acc1[4], 0.f); q1.y = fmaxf(acc1[5], 0.f);
        q1.z = fmaxf(acc1[6], 0.f); q1.w = fmaxf(acc1[7], 0.f);
        *(float4*)(mu_out + o1) = q0;
        *(float4*)(mu_out + o1 + 4) = q1;
    }
}

// ---- s conv via bf16 MFMA, LDS-free. Each wave: 16 pixels x 64 cout.
// s stored as hi+lo bf16 pair -> 2 MFMAs per (chunk, n-tile).
// s_out = (mu_out>0) ? q9*softplus + sum s*w^2 : 0.
__global__ void __launch_bounds__(256)
smfma_kernel(const unsigned short* __restrict__ s1h, const unsigned short* __restrict__ s1l,
             const unsigned short* __restrict__ s2h, const unsigned short* __restrict__ s2l,
             const float* __restrict__ q9v,
             const unsigned short* __restrict__ wTsq,
             const float* __restrict__ spv_,
             const float* __restrict__ muG,
             unsigned short* __restrict__ outH, unsigned short* __restrict__ outL,
             float* __restrict__ outF,
             int B_, int H, int W, int Cin1, int Cin2,
             int H2, int W2, int dh, int dw, int Cout)
{
    const int lane = threadIdx.x & 63;
    const int wave = threadIdx.x >> 6;
    const int total = B_ * H * W;
    const int Cin = Cin1 + Cin2;
    const int pixBase = blockIdx.x * 64 + wave * 16;
    const int coBase = blockIdx.y * 64;
    const int row = lane & 15;
    const int quad = lane >> 4;

    int P = pixBase + row;
    bool pv = P < total;
    int Pc = pv ? P : 0;
    int pb = Pc / (H * W);
    int r0i = Pc - pb * (H * W);
    int ph = r0i / W;
    int pw = r0i - ph * W;

    floatx4 acc[4];
#pragma unroll
    for (int i = 0; i < 4; i++) acc[i] = (floatx4){0.f, 0.f, 0.f, 0.f};
    const short8 zero8 = {0, 0, 0, 0, 0, 0, 0, 0};

    for (int tap = 0; tap < 9; tap++) {
        int kh = tap / 3, kw = tap - kh * 3;
        int ih = ph + kh - 1, iw = pw + kw - 1;
        bool tv = pv && ((unsigned)ih < (unsigned)H) && ((unsigned)iw < (unsigned)W);
        // source 1
        {
            size_t ab = ((size_t)(pb * H + ih) * W + iw) * (size_t)Cin1 + quad * 8;
            const unsigned short* __restrict__ wrow =
                wTsq + (size_t)(tap * Cout + coBase) * Cin + quad * 8;
            for (int kb = 0; kb < Cin1; kb += 32) {
                short8 ah = zero8, al = zero8;
                if (tv) {
                    ah = *(const short8*)(s1h + ab + kb);
                    al = *(const short8*)(s1l + ab + kb);
                }
#pragma unroll
                for (int nt = 0; nt < 4; nt++) {
                    short8 bf = *(const short8*)(wrow + (size_t)(nt * 16 + row) * Cin + kb);
                    acc[nt] = __builtin_amdgcn_mfma_f32_16x16x32_bf16(ah, bf, acc[nt], 0, 0, 0);
                    acc[nt] = __builtin_amdgcn_mfma_f32_16x16x32_bf16(al, bf, acc[nt], 0, 0, 0);
                }
            }
        }
        // source 2 (fused skip concat)
        if (Cin2 > 0) {
            size_t ab = ((size_t)(pb * H2 + ih + dh) * W2 + (iw + dw)) * (size_t)Cin2 + quad * 8;
            const unsigned short* __restrict__ wrow =
                wTsq + (size_t)(tap * Cout + coBase) * Cin + Cin1 + quad * 8;
            for (int kb = 0; kb < Cin2; kb += 32) {
                short8 ah = zero8, al = zero8;
                if (tv) {
                    ah = *(const short8*)(s2h + ab + kb);
                    al = *(const short8*)(s2l + ab + kb);
                }
#pragma unroll
                for (int nt = 0; nt < 4; nt++) {
                    short8 bf = *(const short8*)(wrow + (size_t)(nt * 16 + row) * Cin + kb);
                    acc[nt] = __builtin_amdgcn_mfma_f32_16x16x32_bf16(ah, bf, acc[nt], 0, 0, 0);
                    acc[nt] = __builtin_amdgcn_mfma_f32_16x16x32_bf16(al, bf, acc[nt], 0, 0, 0);
                }
            }
        }
    }

    // epilogue: D layout col(lane&15)=co, row(quad*4+r)=pixel
#pragma unroll
    for (int nt = 0; nt < 4; nt++) {
        int co = coBase + nt * 16 + row;
        float spv = spv_[co];
        floatx4 a = acc[nt];
#pragma unroll
        for (int r = 0; r < 4; r++) {
            int P2 = pixBase + quad * 4 + r;
            if (P2 < total) {
                size_t o = (size_t)P2 * Cout + co;
                float g = muG[o];
                float s = (g > 0.f) ? (q9v[P2] * spv + a[r]) : 0.f;
                if (outF) outF[o] = s;
                if (outH) {
                    unsigned short hh = f2bf(s);
                    outH[o] = hh;
                    outL[o] = f2bf(s - bfval(hh));
                }
            }
        }
    }
}

// ---- first layer (Cin=3): mu fp32 + s hi/lo
__global__ void conv_input_relu_kernel(const float* __restrict__ x,
                                       const float* __restrict__ w_mu,
                                       const float* __restrict__ w_sig,
                                       float* __restrict__ mu_out,
                                       unsigned short* __restrict__ s_hi,
                                       unsigned short* __restrict__ s_lo,
                                       int B_, int H, int W, int Cin, int Cout)
{
    int co = threadIdx.x;
    int pix = blockIdx.x * blockDim.y + threadIdx.y;
    int total = B_ * H * W;
    if (pix >= total) return;
    int b = pix / (H * W);
    int rem = pix % (H * W);
    int h = rem / W, w = rem % W;

    float mu = 0.f, q = 0.f;
    for (int kh = 0; kh < 3; kh++) {
        int ih = h + kh - 1;
        if (ih < 0 || ih >= H) continue;
        for (int kw = 0; kw < 3; kw++) {
            int iw = w + kw - 1;
            if (iw < 0 || iw >= W) continue;
            const float* xp = x + ((size_t)(b * H + ih) * W + iw) * Cin;
            const float* wp = w_mu + (size_t)((kh * 3 + kw) * Cin) * Cout + co;
            for (int ci = 0; ci < Cin; ci++) {
                float xv = xp[ci];
                mu += xv * wp[(size_t)ci * Cout];
                q += xv * xv;
            }
        }
    }
    float s = q * softplus_f(w_sig[co]);
    if (!(mu > 0.f)) { mu = 0.f; s = 0.f; }
    size_t oidx = (size_t)pix * Cout + co;
    mu_out[oidx] = mu;
    unsigned short hh = f2bf(s);
    s_hi[oidx] = hh;
    s_lo[oidx] = f2bf(s - bfval(hh));
}

// ---- unpool+conv (fp32 vector, in-register w^2, tq precomputed):
// mu out fp32 (relu'd), s out hi/lo bf16
__global__ void __launch_bounds__(256)
conv_unpool_fused(const float* __restrict__ mu_in,
                  const float* __restrict__ s_in,
                  const float* __restrict__ tq,
                  const float* __restrict__ w_mu,
                  const float* __restrict__ w_sig,
                  float* __restrict__ mu_out,
                  unsigned short* __restrict__ s_hi,
                  unsigned short* __restrict__ s_lo,
                  int B_, int Hin, int Win, int Cin,
                  int Hout, int Wout, int Cout)
{
    int cog = threadIdx.x * 4;
    int pix = blockIdx.x * blockDim.y + threadIdx.y;
    int total = B_ * Hout * Wout;
    if (pix >= total) return;
    int b = pix / (Hout * Wout);
    int rem = pix - b * (Hout * Wout);
    int ho = rem / Wout, wo = rem - (rem / Wout) * Wout;

    int khs[2], ihs[2], nkh;
    if (ho & 1) { nkh = 2; khs[0] = 0; ihs[0] = (ho - 1) >> 1; khs[1] = 2; ihs[1] = (ho + 1) >> 1; }
    else        { nkh = 1; khs[0] = 1; ihs[0] = ho >> 1; }
    int kws[2], iws[2], nkw;
    if (wo & 1) { nkw = 2; kws[0] = 0; iws[0] = (wo - 1) >> 1; kws[1] = 2; iws[1] = (wo + 1) >> 1; }
    else        { nkw = 1; kws[0] = 1; iws[0] = wo >> 1; }

    float4 amu = make_float4(0.f, 0.f, 0.f, 0.f);
    float4 asa = make_float4(0.f, 0.f, 0.f, 0.f);
    float q = 0.f;

    for (int a = 0; a < nkh; a++) {
        for (int c = 0; c < nkw; c++) {
            q += tq[(size_t)(b * Hin + ihs[a]) * Win + iws[c]];
            size_t base = ((size_t)(b * Hin + ihs[a]) * Win + iws[c]) * Cin;
            const float* mp = mu_in + base;
            const float* sp = s_in + base;
            const float* wp = w_mu + (size_t)((khs[a] * 3 + kws[c]) * Cin) * Cout + cog;
            for (int ci = 0; ci < Cin; ci += 4) {
                float4 m4 = *(const float4*)(mp + ci);
                float4 s4 = *(const float4*)(sp + ci);
                const float* wb = wp + (size_t)ci * Cout;
                float4 w0 = *(const float4*)(wb);
                float4 w1 = *(const float4*)(wb + Cout);
                float4 w2 = *(const float4*)(wb + 2 * Cout);
                float4 w3 = *(const float4*)(wb + 3 * Cout);
                amu.x += m4.x*w0.x + m4.y*w1.x + m4.z*w2.x + m4.w*w3.x;
                amu.y += m4.x*w0.y + m4.y*w1.y + m4.z*w2.y + m4.w*w3.y;
                amu.z += m4.x*w0.z + m4.y*w1.z + m4.z*w2.z + m4.w*w3.z;
                amu.w += m4.x*w0.w + m4.y*w1.w + m4.z*w2.w + m4.w*w3.w;
                asa.x += s4.x*(w0.x*w0.x) + s4.y*(w1.x*w1.x) + s4.z*(w2.x*w2.x) + s4.w*(w3.x*w3.x);
                asa.y += s4.x*(w0.y*w0.y) + s4.y*(w1.y*w1.y) + s4.z*(w2.y*w2.y) + s4.w*(w3.y*w3.y);
                asa.z += s4.x*(w0.z*w0.z) + s4.y*(w1.z*w1.z) + s4.z*(w2.z*w2.z) + s4.w*(w3.z*w3.z);
                asa.w += s4.x*(w0.w*w0.w) + s4.y*(w1.w*w1.w) + s4.z*(w2.w*w2.w) + s4.w*(w3.w*w3.w);
            }
        }
    }
    float4 sg = *(const float4*)(w_sig + cog);
    float4 so;
    so.x = q * softplus_f(sg.x) + asa.x;
    so.y = q * softplus_f(sg.y) + asa.y;
    so.z = q * softplus_f(sg.z) + asa.z;
    so.w = q * softplus_f(sg.w) + asa.w;
    if (!(amu.x > 0.f)) { amu.x = 0.f; so.x = 0.f; }
    if (!(amu.y > 0.f)) { amu.y = 0.f; so.y = 0.f; }
    if (!(amu.z > 0.f)) { amu.z = 0.f; so.z = 0.f; }
    if (!(amu.w > 0.f)) { amu.w = 0.f; so.w = 0.f; }
    size_t oidx = (size_t)pix * Cout + cog;
    *(float4*)(mu_out + oidx) = amu;
    unsigned short h0 = f2bf(so.x), h1 = f2bf(so.y), h2 = f2bf(so.z), h3 = f2bf(so.w);
    s_hi[oidx] = h0; s_hi[oidx + 1] = h1; s_hi[oidx + 2] = h2; s_hi[oidx + 3] = h3;
    s_lo[oidx]     = f2bf(so.x - bfval(h0));
    s_lo[oidx + 1] = f2bf(so.y - bfval(h1));
    s_lo[oidx + 2] = f2bf(so.z - bfval(h2));
    s_lo[oidx + 3] = f2bf(so.w - bfval(h3));
}

// ---- pool: mu fp32, s hi/lo gather at argmax
__global__ void pool_kernel(const float* __restrict__ mu_in,
                            const unsigned short* __restrict__ s_h,
                            const unsigned short* __restrict__ s_l,
                            float* __restrict__ mu_out,
                            unsigned short* __restrict__ so_h,
                            unsigned short* __restrict__ so_l,
                            int B_, int H, int W, int C)
{
    int Ho = H / 2, Wo = W / 2;
    size_t total = (size_t)B_ * Ho * Wo * C;
    size_t idx = (size_t)blockIdx.x * blockDim.x + threadIdx.x;
    if (idx >= total) return;
    int c = idx % C;
    size_t t = idx / C;
    int w = t % Wo; t /= Wo;
    int h = t % Ho;
    int b = t / Ho;
    size_t i0 = ((size_t)(b * H + 2 * h) * W + 2 * w) * C + c;
    size_t rowStride = (size_t)W * C;
    float m00 = mu_in[i0], m01 = mu_in[i0 + C];
    float m10 = mu_in[i0 + rowStride], m11 = mu_in[i0 + rowStride + C];
    int best = 0; float bm = m00;
    if (m01 > bm) { bm = m01; best = 1; }
    if (m10 > bm) { bm = m10; best = 2; }
    if (m11 > bm) { bm = m11; best = 3; }
    size_t off = (size_t)(best >> 1) * rowStride + (size_t)(best & 1) * C;
    mu_out[idx] = bm;
    so_h[idx] = s_h[i0 + off];
    so_l[idx] = s_l[i0 + off];
}

// ---- final 1x1 conv_inter + C=2 softmax density prop (fp32 in)
__global__ void final_kernel(const float* __restrict__ mu_in,
                             const float* __restrict__ s_in,
                             const float* __restrict__ w_mu,
                             const float* __restrict__ w_sig,
                             float* __restrict__ out,
                             int B_, int H, int W, int Cin)
{
    int pix = blockIdx.x * blockDim.x + threadIdx.x;
    int total = B_ * H * W;
    if (pix >= total) return;
    const float* mp = mu_in + (size_t)pix * Cin;
    const float* sp = s_in + (size_t)pix * Cin;
    float mu0 = 0.f, mu1 = 0.f, s0a = 0.f, s1a = 0.f, q = 0.f;
    for (int ci = 0; ci < Cin; ci += 4) {
        float4 m = *(const float4*)(mp + ci);
        float4 s = *(const float4*)(sp + ci);
        float4 wa = *(const float4*)(w_mu + ci * 2);
        float4 wb = *(const float4*)(w_mu + ci * 2 + 4);
        mu0 += m.x * wa.x + m.y * wa.z + m.z * wb.x + m.w * wb.z;
        mu1 += m.x * wa.y + m.y * wa.w + m.z * wb.y + m.w * wb.w;
        s0a += s.x * (wa.x * wa.x) + s.y * (wa.z * wa.z) + s.z * (wb.x * wb.x) + s.w * (wb.z * wb.z);
        s1a += s.x * (wa.y * wa.y) + s.y * (wa.w * wa.w) + s.z * (wb.y * wb.y) + s.w * (wb.w * wb.w);
        q += m.x * m.x + s.x + m.y * m.y + s.y + m.z * m.z + s.z + m.w * m.w + s.w;
    }
    float s0 = q * softplus_f(w_sig[0]) + s0a;
    float s1 = q * softplus_f(w_sig[1]) + s1a;
    float mx = fmaxf(mu0, mu1);
    float e0 = expf(mu0 - mx), e1 = expf(mu1 - mx);
    float inv = 1.f / (e0 + e1);
    float p0 = e0 * inv, p1 = e1 * inv;
    float g00 = p0 - p0 * p0, g01 = -p0 * p1;
    float g10 = -p1 * p0,     g11 = p1 - p1 * p1;
    float so0 = g00 * g00 * s0 + g01 * g01 * s1;
    float so1 = g10 * g10 * s0 + g11 * g11 * s1;
    out[(size_t)pix * 2]     = p0;
    out[(size_t)pix * 2 + 1] = p1;
    size_t off = (size_t)total * 2;
    out[off + (size_t)pix * 2]     = so0;
    out[off + (size_t)pix * 2 + 1] = so1;
}

// ---------------------------------------------------------------------------

extern "C" void kernel_launch(void* const* d_in, const int* in_sizes, int n_in,
                              void* d_out, int out_size, void* d_ws, size_t ws_size,
                              hipStream_t stream)
{
    const float* x = (const float*)d_in[0];
    enum { E1A, E1B, E2A, E2B, BA, BB, D2U, D2A, D2B, D1U, D1A, D1B, FIN, NW };
    const float* wmu[NW];
    const float* wsig[NW];
    for (int i = 0; i < NW; i++) {
        wmu[i]  = (const float*)d_in[1 + 2 * i];
        wsig[i] = (const float*)d_in[2 + 2 * i];
    }

    const int B_ = 4;
    float* ws = (float*)d_ws;
    float* M0   = ws;                        // 4194304
    float* M1   = ws + 4194304;              // 4194304
    float* E1mu = ws + 8388608;              // 4194304
    float* E2mu = ws + 12582912;             // 2097152
    float* SF   = ws + 14680064;             // 4194304 (fp32 s where needed)
    float* tq   = ws + 18874368;             // 65536
    float* q9   = ws + 18939904;             // 65536
    float* spb  = ws + 19005440;             // 2048
    unsigned short* us = (unsigned short*)(ws + 19007488);
    unsigned short* bS0h  = us;              // 4194304 each
    unsigned short* bS0l  = us + 4194304;
    unsigned short* bS1h  = us + 8388608;
    unsigned short* bS1l  = us + 12582912;
    unsigned short* bE1sh = us + 16777216;
    unsigned short* bE1sl = us + 20971520;
    unsigned short* bE2sh = us + 25165824;   // 2097152 each
    unsigned short* bE2sl = us + 27262976;
    unsigned short* wTsq  = us + 29360128;   // 1695744

    // MFMA layer table
    const int mlay[9]  = {E1B, E2A, E2B, BA, BB, D2A, D2B, D1A, D1B};
    const int mcin[9]  = {64, 64, 128, 128, 256, 256, 128, 128, 64};
    const int mcout[9] = {64, 128, 128, 256, 256, 128, 128, 64, 64};
    size_t woff[NW]; int spoff[NW];
    {
        size_t wo = 0; int so = 0;
        for (int i = 0; i < 9; i++) {
            int l = mlay[i];
            woff[l] = wo; spoff[l] = so;
            int n = 9 * mcin[i] * mcout[i];
            wprep_kernel<<<dim3((n + 255) / 256), dim3(256), 0, stream>>>(
                wmu[l], wTsq + wo, mcin[i], mcout[i], n);
            sp_kernel<<<dim3(1), dim3(256), 0, stream>>>(wsig[l], spb + so, mcout[i]);
            wo += n; so += mcout[i];
        }
    }

    // full hybrid layer: t/q9 + mu vector conv (2px/thread) + s MFMA
    auto layer = [&](const float* muIn, const unsigned short* sInH, const unsigned short* sInL,
                     int ci1,
                     const float* skMu, const unsigned short* skSH, const unsigned short* skSL,
                     int ci2, int h2, int w2, int dh, int dw,
                     int H, int W, int widx, int cout,
                     float* muOut, unsigned short* oH, unsigned short* oL, float* oF) {
        int total = B_ * H * W;
        t_mixed_kernel<<<dim3((total + 255) / 256), dim3(256), 0, stream>>>(
            muIn, sInH, sInL, skMu, skSH, skSL, tq, B_, H, W, ci1, ci2, h2, w2, dh, dw);
        q9_kernel<<<dim3((total + 255) / 256), dim3(256), 0, stream>>>(tq, q9, B_, H, W);
        int Wp = (W + 1) / 2;
        int totalP = B_ * H * Wp;
        int tx = cout / 8, ty = 256 / tx;
        muconv_kernel<<<dim3((totalP + ty - 1) / ty), dim3(tx, ty), 0, stream>>>(
            muIn, skMu, wmu[widx], muOut, B_, H, W, ci1, ci2, h2, w2, dh, dw, cout);
        smfma_kernel<<<dim3((total + 63) / 64, cout / 64), dim3(256), 0, stream>>>(
            sInH, sInL, skSH, skSL, q9, wTsq + woff[widx], spb + spoff[widx], muOut,
            oH, oL, oF, B_, H, W, ci1, ci2, h2, w2, dh, dw, cout);
    };

    auto unpool = [&](const float* mi, const float* si,
                      int hi, int wi, int ci, int ho, int wo, int co, int widx,
                      float* muOut, unsigned short* sH, unsigned short* sL) {
        int nin = B_ * hi * wi;
        t_f32_kernel<<<dim3((nin + 255) / 256), dim3(256), 0, stream>>>(mi, si, tq, nin, ci);
        int totalPix = B_ * ho * wo;
        int tx = co / 4, ty = 256 / tx;
        conv_unpool_fused<<<dim3((totalPix + ty - 1) / ty), dim3(tx, ty), 0, stream>>>(
            mi, si, tq, wmu[widx], wsig[widx], muOut, sH, sL,
            B_, hi, wi, ci, ho, wo, co);
    };

    // ---- encoder level 1 ----
    {
        int totalPix = B_ * 128 * 128;
        conv_input_relu_kernel<<<dim3((totalPix + 3) / 4), dim3(64, 4), 0, stream>>>(
            x, wmu[E1A], wsig[E1A], M0, bS0h, bS0l, B_, 128, 128, 3, 64);
    }
    layer(M0, bS0h, bS0l, 64, nullptr, nullptr, nullptr, 0, 0, 0, 0, 0,
          128, 128, E1B, 64, E1mu, bE1sh, bE1sl, nullptr);
    {
        size_t total = (size_t)B_ * 64 * 64 * 64;
        pool_kernel<<<dim3((total + 255) / 256), dim3(256), 0, stream>>>(
            E1mu, bE1sh, bE1sl, M0, bS0h, bS0l, B_, 128, 128, 64);
    }
    // ---- encoder level 2 ----
    layer(M0, bS0h, bS0l, 64, nullptr, nullptr, nullptr, 0, 0, 0, 0, 0,
          64, 64, E2A, 128, M1, bS1h, bS1l, nullptr);
    layer(M1, bS1h, bS1l, 128, nullptr, nullptr, nullptr, 0, 0, 0, 0, 0,
          64, 64, E2B, 128, E2mu, bE2sh, bE2sl, nullptr);
    {
        size_t total = (size_t)B_ * 32 * 32 * 128;
        pool_kernel<<<dim3((total + 255) / 256), dim3(256), 0, stream>>>(
            E2mu, bE2sh, bE2sl, M0, bS0h, bS0l, B_, 64, 64, 128);
    }
    // ---- bottleneck ----
    layer(M0, bS0h, bS0l, 128, nullptr, nullptr, nullptr, 0, 0, 0, 0, 0,
          32, 32, BA, 256, M1, bS1h, bS1l, nullptr);
    layer(M1, bS1h, bS1l, 256, nullptr, nullptr, nullptr, 0, 0, 0, 0, 0,
          32, 32, BB, 256, M0, nullptr, nullptr, SF);
    // ---- decoder level 2 ----
    unpool(M0, SF, 32, 32, 256, 63, 63, 128, D2U, M1, bS1h, bS1l);
    layer(M1, bS1h, bS1l, 128, E2mu, bE2sh, bE2sl, 128, 64, 64, 0, 0,
          63, 63, D2A, 128, M0, bS0h, bS0l, nullptr);
    layer(M0, bS0h, bS0l, 128, nullptr, nullptr, nullptr, 0, 0, 0, 0, 0,
          63, 63, D2B, 128, M1, nullptr, nullptr, SF);
    // ---- decoder level 1 ----
    unpool(M1, SF, 63, 63, 128, 125, 125, 64, D1U, M0, bS0h, bS0l);
    layer(M0, bS0h, bS0l, 64, E1mu, bE1sh, bE1sl, 64, 128, 128, 1, 1,
          125, 125, D1A, 64, M1, bS1h, bS1l, nullptr);
    layer(M1, bS1h, bS1l, 64, nullptr, nullptr, nullptr, 0, 0, 0, 0, 0,
          125, 125, D1B, 64, M0, nullptr, nullptr, SF);
    // ---- final 1x1 + softmax prop ----
    {
        int totalPix = B_ * 125 * 125;
        final_kernel<<<dim3((totalPix + 63) / 64), dim3(64), 0, stream>>>(
            M0, SF, wmu[FIN], wsig[FIN], (float*)d_out, B_, 125, 125, 64);
    }
}